// Round 1
// baseline (17642.508 us; speedup 1.0000x reference)
//
#include <hip/hip_runtime.h>
#include <math.h>

#define NN 100000
#define NE 1600000

__device__ __forceinline__ unsigned fkey(float f) {
    unsigned b = __float_as_uint(f);
    return (b & 0x80000000u) ? ~b : (b | 0x80000000u);
}
__device__ __forceinline__ float finv(unsigned k) {
    unsigned b = (k & 0x80000000u) ? (k & 0x7FFFFFFFu) : ~k;
    return __uint_as_float(b);
}
__device__ __forceinline__ float lrelu(float x) { return x > 0.f ? x : 0.2f * x; }
__device__ __forceinline__ float elu1(float x) { return x > 0.f ? x : (__expf(x) - 1.f); }

// ---- degree + edge_attr sum per dst (for self-loop mean fill) ----
__global__ void k_deg(const int* __restrict__ dst, const float* __restrict__ ea,
                      float* __restrict__ deg, float* __restrict__ asum) {
    int i = blockIdx.x * blockDim.x + threadIdx.x;
    if (i >= NE) return;
    int d = dst[i];
    atomicAdd(deg + d, 1.0f);
    atomicAdd(asum + 2 * d,     ea[2 * i]);
    atomicAdd(asum + 2 * d + 1, ea[2 * i + 1]);
}

__global__ void k_loop(const float* __restrict__ deg, float* __restrict__ la) {
    int n = blockIdx.x * blockDim.x + threadIdx.x;
    if (n >= NN) return;
    float d = fmaxf(deg[n], 1.0f);
    la[2 * n]     /= d;
    la[2 * n + 1] /= d;
}

// ---- node transform: h[n, j] = sum_i x[n,i] * W[i,j] ----
template <int IN, int HC>
__global__ void k_nodeh(const float* __restrict__ x, const float* __restrict__ W,
                        float* __restrict__ h) {
    int idx = blockIdx.x * blockDim.x + threadIdx.x;
    if (idx >= NN * HC) return;
    int n = idx / HC, j = idx % HC;
    const float* xr = x + (size_t)n * IN;
    float acc = 0.f;
#pragma unroll
    for (int i = 0; i < IN; i++) acc += xr[i] * W[i * HC + j];
    h[idx] = acc;
}

// ---- Me[d,h] = sum_c We[d, h*C+c] * aE[h,c]  (tiny, 2*H values) ----
template <int H, int C>
__global__ void k_me(const float* __restrict__ We, const float* __restrict__ aE,
                     float* __restrict__ me) {
    int t = threadIdx.x;
    if (t >= 2 * H) return;
    int d = t / H, hd = t % H;
    float s = 0.f;
    for (int c = 0; c < C; c++) s += We[d * H * C + hd * C + c] * aE[hd * C + c];
    me[t] = s;  // me[d*H + hd]
}

// ---- per-node: al_src, al_dst, self-loop alpha, init m ----
template <int H, int C>
__global__ void k_al(const float* __restrict__ h, const float* __restrict__ aS,
                     const float* __restrict__ aD, const float* __restrict__ la,
                     const float* __restrict__ me, float* __restrict__ als,
                     float* __restrict__ ald, float* __restrict__ aself,
                     unsigned* __restrict__ mkey) {
    int t = blockIdx.x * blockDim.x + threadIdx.x;
    if (t >= NN * H) return;
    int n = t / H, hd = t % H;
    const float* hr = h + (size_t)n * H * C + hd * C;
    float s1 = 0.f, s2 = 0.f;
#pragma unroll
    for (int c = 0; c < C; c++) {
        float v = hr[c];
        s1 += v * aS[hd * C + c];
        s2 += v * aD[hd * C + c];
    }
    als[t] = s1;
    ald[t] = s2;
    float a = lrelu(s1 + s2 + la[2 * n] * me[hd] + la[2 * n + 1] * me[H + hd]);
    aself[t] = a;
    mkey[t] = fkey(a);  // init segment-max with self-loop alpha
}

// ---- edge pass 1: alpha per (edge, head); atomicMax into m ----
template <int H>
__global__ void k_edge1(const int* __restrict__ src, const int* __restrict__ dst,
                        const float* __restrict__ ea, const float* __restrict__ als,
                        const float* __restrict__ ald, const float* __restrict__ me,
                        float* __restrict__ alpha, unsigned* __restrict__ mkey) {
    int t = blockIdx.x * blockDim.x + threadIdx.x;
    if (t >= NE * H) return;
    int e = t / H, hd = t % H;
    int s = src[e], d = dst[e];
    float a = lrelu(als[s * H + hd] + ald[d * H + hd] +
                    ea[2 * e] * me[hd] + ea[2 * e + 1] * me[H + hd]);
    alpha[t] = a;
    atomicMax(mkey + d * H + hd, fkey(a));
}

// ---- edge pass 2: w = exp(alpha - m); scatter-add den and w*h[src] ----
template <int H, int C>
__global__ void k_edge2(const int* __restrict__ src, const int* __restrict__ dst,
                        const float* __restrict__ alpha, const unsigned* __restrict__ mkey,
                        const float* __restrict__ h, float* __restrict__ den,
                        float* __restrict__ accum) {
    int t = blockIdx.x * blockDim.x + threadIdx.x;
    if (t >= NE * H) return;
    int e = t / H, hd = t % H;
    int s = src[e], d = dst[e];
    float w = __expf(alpha[t] - finv(mkey[d * H + hd]));
    atomicAdd(den + d * H + hd, w);
    const float* hs = h + (size_t)s * H * C + hd * C;
    float* ad = accum + (size_t)d * H * C + hd * C;
    if (C == 1) {
        atomicAdd(ad, w * hs[0]);
    } else {
#pragma unroll
        for (int c = 0; c < C; c += 4) {
            float4 v = *(const float4*)(hs + c);
            atomicAdd(ad + c,     w * v.x);
            atomicAdd(ad + c + 1, w * v.y);
            atomicAdd(ad + c + 2, w * v.z);
            atomicAdd(ad + c + 3, w * v.w);
        }
    }
}

// ---- finalize: add self-loop term, normalize, bias, activation ----
// MODE 0: ELU -> out buffer (may alias h). MODE 1: sigmoid -> out.
template <int H, int C, int MODE>
__global__ void k_fin(const float* __restrict__ accum, const float* __restrict__ den,
                      const float* __restrict__ aself, const unsigned* __restrict__ mkey,
                      const float* __restrict__ h, const float* __restrict__ b,
                      float* __restrict__ out) {
    int idx = blockIdx.x * blockDim.x + threadIdx.x;
    if (idx >= NN * H * C) return;
    int n = idx / (H * C), j = idx % (H * C), hd = j / C;
    float mf = finv(mkey[n * H + hd]);
    float wself = __expf(aself[n * H + hd] - mf);
    float dt = den[n * H + hd] + wself;
    float v = (accum[idx] + wself * h[idx]) / dt + b[j];
    if (MODE == 0)
        v = elu1(v);
    else
        v = 1.f / (1.f + __expf(-v));
    out[idx] = v;
}

extern "C" void kernel_launch(void* const* d_in, const int* in_sizes, int n_in,
                              void* d_out, int out_size, void* d_ws, size_t ws_size,
                              hipStream_t stream) {
    const float* x   = (const float*)d_in[0];
    const int*   ei  = (const int*)d_in[1];
    const float* ea  = (const float*)d_in[2];
    const float* W1  = (const float*)d_in[3];
    const float* aS1 = (const float*)d_in[4];
    const float* aD1 = (const float*)d_in[5];
    const float* We1 = (const float*)d_in[6];
    const float* aE1 = (const float*)d_in[7];
    const float* b1  = (const float*)d_in[8];
    const float* W2  = (const float*)d_in[9];
    const float* aS2 = (const float*)d_in[10];
    const float* aD2 = (const float*)d_in[11];
    const float* We2 = (const float*)d_in[12];
    const float* aE2 = (const float*)d_in[13];
    const float* b2  = (const float*)d_in[14];
    const float* W3  = (const float*)d_in[15];
    const float* aS3 = (const float*)d_in[16];
    const float* aD3 = (const float*)d_in[17];
    const float* We3 = (const float*)d_in[18];
    const float* aE3 = (const float*)d_in[19];
    const float* b3  = (const float*)d_in[20];

    const int* srcv = ei;
    const int* dstv = ei + NE;

    // ---- workspace carve-out (all re-initialized every call) ----
    char* base = (char*)d_ws;
    size_t off = 0;
    auto alloc = [&](size_t nbytes) -> void* {
        void* p = base + off;
        off += (nbytes + 255) & ~(size_t)255;
        return p;
    };
    float*    deg   = (float*)alloc((size_t)NN * 4);
    float*    la    = (float*)alloc((size_t)NN * 8);
    float*    als   = (float*)alloc((size_t)NN * 16);
    float*    ald   = (float*)alloc((size_t)NN * 16);
    float*    aself = (float*)alloc((size_t)NN * 16);
    unsigned* mkey  = (unsigned*)alloc((size_t)NN * 16);
    float*    den   = (float*)alloc((size_t)NN * 16);
    float*    me    = (float*)alloc(256);
    float*    h3    = (float*)alloc((size_t)NN * 4);
    float*    acc3  = (float*)alloc((size_t)NN * 4);
    float*    alpha = (float*)alloc((size_t)NE * 16);
    float*    A     = (float*)alloc((size_t)NN * 128 * 4);
    float*    B     = (float*)alloc((size_t)NN * 128 * 4);
    (void)ws_size; (void)in_sizes; (void)n_in; (void)out_size;

    auto cdiv = [](long long a, long long b) { return (int)((a + b - 1) / b); };
    const int BS = 256;

    // ---- shared preprocessing: deg + self-loop mean edge_attr ----
    hipMemsetAsync(deg, 0, (size_t)NN * 4, stream);
    hipMemsetAsync(la, 0, (size_t)NN * 8, stream);
    k_deg<<<cdiv(NE, BS), BS, 0, stream>>>(dstv, ea, deg, la);
    k_loop<<<cdiv(NN, BS), BS, 0, stream>>>(deg, la);

    // ================= Layer 1: IN=5, H=4, C=32 (ELU) =================
    k_nodeh<5, 128><<<cdiv((long long)NN * 128, BS), BS, 0, stream>>>(x, W1, A);
    k_me<4, 32><<<1, 64, 0, stream>>>(We1, aE1, me);
    k_al<4, 32><<<cdiv((long long)NN * 4, BS), BS, 0, stream>>>(A, aS1, aD1, la, me,
                                                                als, ald, aself, mkey);
    k_edge1<4><<<cdiv((long long)NE * 4, BS), BS, 0, stream>>>(srcv, dstv, ea, als, ald,
                                                               me, alpha, mkey);
    hipMemsetAsync(den, 0, (size_t)NN * 16, stream);
    hipMemsetAsync(B, 0, (size_t)NN * 128 * 4, stream);
    k_edge2<4, 32><<<cdiv((long long)NE * 4, BS), BS, 0, stream>>>(srcv, dstv, alpha, mkey,
                                                                   A, den, B);
    k_fin<4, 32, 0><<<cdiv((long long)NN * 128, BS), BS, 0, stream>>>(B, den, aself, mkey,
                                                                      A, b1, A);  // act1 -> A

    // ================= Layer 2: IN=128, H=2, C=32 (ELU) =================
    k_nodeh<128, 64><<<cdiv((long long)NN * 64, BS), BS, 0, stream>>>(A, W2, B);  // h2 -> B
    k_me<2, 32><<<1, 64, 0, stream>>>(We2, aE2, me);
    k_al<2, 32><<<cdiv((long long)NN * 2, BS), BS, 0, stream>>>(B, aS2, aD2, la, me,
                                                                als, ald, aself, mkey);
    k_edge1<2><<<cdiv((long long)NE * 2, BS), BS, 0, stream>>>(srcv, dstv, ea, als, ald,
                                                               me, alpha, mkey);
    hipMemsetAsync(den, 0, (size_t)NN * 8, stream);
    hipMemsetAsync(A, 0, (size_t)NN * 64 * 4, stream);
    k_edge2<2, 32><<<cdiv((long long)NE * 2, BS), BS, 0, stream>>>(srcv, dstv, alpha, mkey,
                                                                   B, den, A);
    k_fin<2, 32, 0><<<cdiv((long long)NN * 64, BS), BS, 0, stream>>>(A, den, aself, mkey,
                                                                     B, b2, B);  // act2 -> B

    // ================= Layer 3: IN=64, H=1, C=1 (sigmoid) =================
    k_nodeh<64, 1><<<cdiv(NN, BS), BS, 0, stream>>>(B, W3, h3);
    k_me<1, 1><<<1, 64, 0, stream>>>(We3, aE3, me);
    k_al<1, 1><<<cdiv(NN, BS), BS, 0, stream>>>(h3, aS3, aD3, la, me, als, ald, aself, mkey);
    k_edge1<1><<<cdiv(NE, BS), BS, 0, stream>>>(srcv, dstv, ea, als, ald, me, alpha, mkey);
    hipMemsetAsync(den, 0, (size_t)NN * 4, stream);
    hipMemsetAsync(acc3, 0, (size_t)NN * 4, stream);
    k_edge2<1, 1><<<cdiv(NE, BS), BS, 0, stream>>>(srcv, dstv, alpha, mkey, h3, den, acc3);
    k_fin<1, 1, 1><<<cdiv(NN, BS), BS, 0, stream>>>(acc3, den, aself, mkey, h3, b3,
                                                    (float*)d_out);
}

// Round 2
// 1026.512 us; speedup vs baseline: 17.1869x; 17.1869x over previous
//
#include <hip/hip_runtime.h>
#include <math.h>

#define NN 100000
#define NE 1600000
#define SCAN_CHUNK 1024
#define SCAN_NB ((NN + SCAN_CHUNK - 1) / SCAN_CHUNK)  // 98

__device__ __forceinline__ float lrelu(float x) { return x > 0.f ? x : 0.2f * x; }
__device__ __forceinline__ float elu1(float x) { return x > 0.f ? x : (__expf(x) - 1.f); }

// ---------- CSR build ----------
__global__ void k_count(const int* __restrict__ dst, const float* __restrict__ ea,
                        int* __restrict__ cnt, float* __restrict__ lasum) {
    int i = blockIdx.x * blockDim.x + threadIdx.x;
    if (i >= NE) return;
    int d = dst[i];
    atomicAdd(cnt + d, 1);
    atomicAdd(lasum + 2 * d,     ea[2 * i]);
    atomicAdd(lasum + 2 * d + 1, ea[2 * i + 1]);
}

__global__ void k_loop(const int* __restrict__ cnt, float* __restrict__ la) {
    int n = blockIdx.x * blockDim.x + threadIdx.x;
    if (n >= NN) return;
    float d = fmaxf((float)cnt[n], 1.0f);
    la[2 * n]     /= d;
    la[2 * n + 1] /= d;
}

// block = 256 threads, each handles 4 consecutive elements of a 1024 chunk
__global__ void k_scanA(const int* __restrict__ cnt, int* __restrict__ rp1,
                        int* __restrict__ bsum) {
    __shared__ int s[256];
    int b = blockIdx.x, t = threadIdx.x;
    int base = b * SCAN_CHUNK + t * 4;
    int v[4], sum = 0;
#pragma unroll
    for (int i = 0; i < 4; i++) {
        v[i] = (base + i < NN) ? cnt[base + i] : 0;
        sum += v[i];
    }
    s[t] = sum;
    __syncthreads();
    for (int off = 1; off < 256; off <<= 1) {
        int x = (t >= off) ? s[t - off] : 0;
        __syncthreads();
        if (t >= off) s[t] += x;
        __syncthreads();
    }
    int run = s[t] - sum;  // exclusive prefix of this thread within block
#pragma unroll
    for (int i = 0; i < 4; i++) {
        run += v[i];
        if (base + i < NN) rp1[base + i] = run;  // inclusive within block
    }
    if (t == 255) bsum[b] = s[255];
}

__global__ void k_scanB(const int* __restrict__ bsum, int* __restrict__ boff) {
    __shared__ int s[128];
    int t = threadIdx.x;
    int v = (t < SCAN_NB) ? bsum[t] : 0;
    s[t] = v;
    __syncthreads();
    for (int off = 1; off < 128; off <<= 1) {
        int x = (t >= off) ? s[t - off] : 0;
        __syncthreads();
        if (t >= off) s[t] += x;
        __syncthreads();
    }
    if (t < SCAN_NB) boff[t] = s[t] - v;  // exclusive
}

__global__ void k_scanC(const int* __restrict__ rp1, const int* __restrict__ boff,
                        const int* __restrict__ cnt, int* __restrict__ rowptr,
                        int* __restrict__ wptr) {
    int i = blockIdx.x * blockDim.x + threadIdx.x;
    if (i >= NN) return;
    int inc = rp1[i] + boff[i / SCAN_CHUNK];
    rowptr[i + 1] = inc;
    wptr[i] = inc - cnt[i];
    if (i == 0) rowptr[0] = 0;
}

__global__ void k_scatter(const int* __restrict__ src, const int* __restrict__ dst,
                          const float* __restrict__ ea, int* __restrict__ wptr,
                          int* __restrict__ esrc, float2* __restrict__ eea) {
    int i = blockIdx.x * blockDim.x + threadIdx.x;
    if (i >= NE) return;
    int d = dst[i];
    int pos = atomicAdd(wptr + d, 1);
    esrc[pos] = src[i];
    eea[pos] = make_float2(ea[2 * i], ea[2 * i + 1]);
}

// ---------- dense node transform ----------
template <int IN, int HC>
__global__ void k_nodeh_lds(const float* __restrict__ x, const float* __restrict__ W,
                            float* __restrict__ h) {
    const int NPB = 256 / HC;
    __shared__ float sx[NPB * IN];
    int nb = blockIdx.x * NPB, t = threadIdx.x;
    for (int i = t; i < NPB * IN; i += 256) {
        int node = nb + i / IN;
        sx[i] = (node < NN) ? x[(size_t)node * IN + i % IN] : 0.f;
    }
    __syncthreads();
    int local = t / HC, j = t % HC;
    int node = nb + local;
    if (node >= NN) return;
    float acc = 0.f;
#pragma unroll
    for (int i = 0; i < IN; i++) acc += sx[local * IN + i] * W[i * HC + j];
    h[(size_t)node * HC + j] = acc;
}

// layer-3 transform: wave per node, 64-lane dot product
__global__ void k_nodeh3(const float* __restrict__ x, const float* __restrict__ W,
                         float* __restrict__ h) {
    int wid = (blockIdx.x * blockDim.x + threadIdx.x) >> 6;
    if (wid >= NN) return;
    int lane = threadIdx.x & 63;
    float p = x[(size_t)wid * 64 + lane] * W[lane];
#pragma unroll
    for (int off = 32; off > 0; off >>= 1) p += __shfl_xor(p, off);
    if (lane == 0) h[wid] = p;
}

// ---------- Me[d,h] = sum_c We[d, h*C+c] * aE[h,c] ----------
template <int H, int C>
__global__ void k_me(const float* __restrict__ We, const float* __restrict__ aE,
                     float* __restrict__ me) {
    int t = threadIdx.x;
    if (t >= 2 * H) return;
    int d = t / H, hd = t % H;
    float s = 0.f;
    for (int c = 0; c < C; c++) s += We[d * H * C + hd * C + c] * aE[hd * C + c];
    me[t] = s;
}

// ---------- per-node attention coefficients ----------
template <int H, int C>
__global__ void k_al(const float* __restrict__ h, const float* __restrict__ aS,
                     const float* __restrict__ aD, float* __restrict__ als,
                     float* __restrict__ ald) {
    int t = blockIdx.x * blockDim.x + threadIdx.x;
    if (t >= NN * H) return;
    int n = t / H, hd = t % H;
    const float* hr = h + (size_t)n * H * C + hd * C;
    float s1 = 0.f, s2 = 0.f;
#pragma unroll
    for (int c = 0; c < C; c++) {
        float v = hr[c];
        s1 += v * aS[hd * C + c];
        s2 += v * aD[hd * C + c];
    }
    als[t] = s1;
    ald[t] = s2;
}

// ---------- fused aggregation: online softmax over CSR, wave per node ----------
// K = HC/64 channels per lane; ELU + bias fused into the epilogue.
template <int H, int C, int K>
__global__ void k_agg(const int* __restrict__ rowptr, const int* __restrict__ esrc,
                      const float2* __restrict__ eea, const float* __restrict__ h,
                      const float* __restrict__ als, const float* __restrict__ ald,
                      const float* __restrict__ la, const float* __restrict__ me,
                      const float* __restrict__ b, float* __restrict__ out) {
    const int HC = 64 * K;
    int n = (blockIdx.x * blockDim.x + threadIdx.x) >> 6;
    if (n >= NN) return;
    int lane = threadIdx.x & 63;
    float la0 = la[2 * n], la1 = la[2 * n + 1];
    int start = rowptr[n], end = rowptr[n + 1];
    float m[K], den[K], acc[K], me0[K], me1[K], aldk[K], bk[K];
    int hd[K], ch[K];
#pragma unroll
    for (int k = 0; k < K; k++) {
        ch[k] = lane + 64 * k;
        hd[k] = ch[k] / C;
        me0[k] = me[hd[k]];
        me1[k] = me[H + hd[k]];
        aldk[k] = ald[n * H + hd[k]];
        float aself = lrelu(als[n * H + hd[k]] + aldk[k] + la0 * me0[k] + la1 * me1[k]);
        m[k] = aself;
        den[k] = 1.f;
        acc[k] = h[(size_t)n * HC + ch[k]];  // * exp(aself - m) = 1
        bk[k] = b[ch[k]];
    }
    for (int e = start; e < end; ++e) {
        int s = esrc[e];
        float2 eav = eea[e];
        size_t hb = (size_t)s * HC;
#pragma unroll
        for (int k = 0; k < K; k++) {
            float a = lrelu(als[s * H + hd[k]] + aldk[k] + eav.x * me0[k] + eav.y * me1[k]);
            float hv = h[hb + ch[k]];
            float mn = fmaxf(m[k], a);
            float sc = __expf(m[k] - mn);
            float p  = __expf(a - mn);
            den[k] = den[k] * sc + p;
            acc[k] = acc[k] * sc + p * hv;
            m[k] = mn;
        }
    }
#pragma unroll
    for (int k = 0; k < K; k++) {
        float v = acc[k] / den[k] + bk[k];
        out[(size_t)n * HC + ch[k]] = elu1(v);
    }
}

// ---------- layer 3: H=1,C=1; wave per node, lanes parallel over edges ----------
__global__ void k_agg3(const int* __restrict__ rowptr, const int* __restrict__ esrc,
                       const float2* __restrict__ eea, const float* __restrict__ h,
                       const float* __restrict__ als, const float* __restrict__ ald,
                       const float* __restrict__ la, const float* __restrict__ me,
                       const float* __restrict__ b, float* __restrict__ out) {
    int n = (blockIdx.x * blockDim.x + threadIdx.x) >> 6;
    if (n >= NN) return;
    int lane = threadIdx.x & 63;
    float me0 = me[0], me1 = me[1];
    float ald_n = ald[n];
    int start = rowptr[n], end = rowptr[n + 1];
    float m = -1e30f, den = 0.f, num = 0.f;
    for (int e = start + lane; e < end; e += 64) {
        int s = esrc[e];
        float2 eav = eea[e];
        float a = lrelu(als[s] + ald_n + eav.x * me0 + eav.y * me1);
        float hv = h[s];
        float mn = fmaxf(m, a);
        float sc = __expf(m - mn);
        float p  = __expf(a - mn);
        den = den * sc + p;
        num = num * sc + p * hv;
        m = mn;
    }
#pragma unroll
    for (int off = 1; off < 64; off <<= 1) {
        float mo = __shfl_xor(m, off);
        float dn = __shfl_xor(den, off);
        float nm = __shfl_xor(num, off);
        float mn = fmaxf(m, mo);
        float s1 = __expf(m - mn), s2 = __expf(mo - mn);
        den = den * s1 + dn * s2;
        num = num * s1 + nm * s2;
        m = mn;
    }
    if (lane == 0) {
        float aself = lrelu(als[n] + ald_n + la[2 * n] * me0 + la[2 * n + 1] * me1);
        float mn = fmaxf(m, aself);
        float sc = __expf(m - mn), ws = __expf(aself - mn);
        den = den * sc + ws;
        num = num * sc + ws * h[n];
        float v = num / den + b[0];
        out[n] = 1.f / (1.f + __expf(-v));
    }
}

extern "C" void kernel_launch(void* const* d_in, const int* in_sizes, int n_in,
                              void* d_out, int out_size, void* d_ws, size_t ws_size,
                              hipStream_t stream) {
    const float* x   = (const float*)d_in[0];
    const int*   ei  = (const int*)d_in[1];
    const float* ea  = (const float*)d_in[2];
    const float* W1  = (const float*)d_in[3];
    const float* aS1 = (const float*)d_in[4];
    const float* aD1 = (const float*)d_in[5];
    const float* We1 = (const float*)d_in[6];
    const float* aE1 = (const float*)d_in[7];
    const float* b1  = (const float*)d_in[8];
    const float* W2  = (const float*)d_in[9];
    const float* aS2 = (const float*)d_in[10];
    const float* aD2 = (const float*)d_in[11];
    const float* We2 = (const float*)d_in[12];
    const float* aE2 = (const float*)d_in[13];
    const float* b2  = (const float*)d_in[14];
    const float* W3  = (const float*)d_in[15];
    const float* aS3 = (const float*)d_in[16];
    const float* aD3 = (const float*)d_in[17];
    const float* We3 = (const float*)d_in[18];
    const float* aE3 = (const float*)d_in[19];
    const float* b3  = (const float*)d_in[20];
    (void)aS3; (void)aD3;  // still used below

    const int* srcv = ei;
    const int* dstv = ei + NE;

    char* basep = (char*)d_ws;
    size_t off = 0;
    auto alloc = [&](size_t nbytes) -> void* {
        void* p = basep + off;
        off += (nbytes + 255) & ~(size_t)255;
        return p;
    };
    int*    cnt    = (int*)alloc((size_t)NN * 4);
    float*  la     = (float*)alloc((size_t)NN * 8);
    int*    rp1    = (int*)alloc((size_t)NN * 4);
    int*    rowptr = (int*)alloc((size_t)(NN + 1) * 4);
    int*    wptr   = (int*)alloc((size_t)NN * 4);
    int*    bsum   = (int*)alloc(512);
    int*    boff   = (int*)alloc(512);
    int*    esrc   = (int*)alloc((size_t)NE * 4);
    float2* eea    = (float2*)alloc((size_t)NE * 8);
    float*  me     = (float*)alloc(256);
    float*  als    = (float*)alloc((size_t)NN * 16);
    float*  ald    = (float*)alloc((size_t)NN * 16);
    float*  A      = (float*)alloc((size_t)NN * 128 * 4);
    float*  B      = (float*)alloc((size_t)NN * 128 * 4);
    float*  h3     = (float*)alloc((size_t)NN * 4);
    (void)ws_size; (void)in_sizes; (void)n_in; (void)out_size;

    auto cdiv = [](long long a, long long b) { return (int)((a + b - 1) / b); };
    const int BS = 256;

    // ---- CSR build (once per call; reused by all 3 layers) ----
    hipMemsetAsync(cnt, 0, (size_t)NN * 4, stream);
    hipMemsetAsync(la, 0, (size_t)NN * 8, stream);
    k_count<<<cdiv(NE, BS), BS, 0, stream>>>(dstv, ea, cnt, la);
    k_loop<<<cdiv(NN, BS), BS, 0, stream>>>(cnt, la);
    k_scanA<<<SCAN_NB, 256, 0, stream>>>(cnt, rp1, bsum);
    k_scanB<<<1, 128, 0, stream>>>(bsum, boff);
    k_scanC<<<cdiv(NN, BS), BS, 0, stream>>>(rp1, boff, cnt, rowptr, wptr);
    k_scatter<<<cdiv(NE, BS), BS, 0, stream>>>(srcv, dstv, ea, wptr, esrc, eea);

    // ================= Layer 1: IN=5, H=4, C=32 (ELU) =================
    k_nodeh_lds<5, 128><<<cdiv(NN, 2), 256, 0, stream>>>(x, W1, A);
    k_me<4, 32><<<1, 64, 0, stream>>>(We1, aE1, me);
    k_al<4, 32><<<cdiv((long long)NN * 4, BS), BS, 0, stream>>>(A, aS1, aD1, als, ald);
    k_agg<4, 32, 2><<<cdiv(NN, 4), 256, 0, stream>>>(rowptr, esrc, eea, A, als, ald,
                                                     la, me, b1, B);  // act1 -> B

    // ================= Layer 2: IN=128, H=2, C=32 (ELU) =================
    k_nodeh_lds<128, 64><<<cdiv(NN, 4), 256, 0, stream>>>(B, W2, A);  // h2 -> A
    k_me<2, 32><<<1, 64, 0, stream>>>(We2, aE2, me);
    k_al<2, 32><<<cdiv((long long)NN * 2, BS), BS, 0, stream>>>(A, aS2, aD2, als, ald);
    k_agg<2, 32, 1><<<cdiv(NN, 4), 256, 0, stream>>>(rowptr, esrc, eea, A, als, ald,
                                                     la, me, b2, B);  // act2 -> B

    // ================= Layer 3: IN=64, H=1, C=1 (sigmoid) =================
    k_nodeh3<<<cdiv(NN, 4), 256, 0, stream>>>(B, W3, h3);
    k_me<1, 1><<<1, 64, 0, stream>>>(We3, aE3, me);
    k_al<1, 1><<<cdiv(NN, BS), BS, 0, stream>>>(h3, aS3, aD3, als, ald);
    k_agg3<<<cdiv(NN, 4), 256, 0, stream>>>(rowptr, esrc, eea, h3, als, ald, la, me,
                                            b3, (float*)d_out);
}

// Round 3
// 869.859 us; speedup vs baseline: 20.2820x; 1.1801x over previous
//
#include <hip/hip_runtime.h>
#include <math.h>

#define NN 100000
#define NE 1600000
#define SCAN_CHUNK 1024
#define SCAN_NB ((NN + SCAN_CHUNK - 1) / SCAN_CHUNK)  // 98

__device__ __forceinline__ float lrelu(float x) { return x > 0.f ? x : 0.2f * x; }
__device__ __forceinline__ float elu1(float x) { return x > 0.f ? x : (__expf(x) - 1.f); }

// ---------- CSR build ----------
__global__ void k_count(const int* __restrict__ dst, int* __restrict__ cnt) {
    int i = blockIdx.x * blockDim.x + threadIdx.x;
    if (i >= NE) return;
    atomicAdd(cnt + dst[i], 1);
}

// block = 256 threads, each handles 4 consecutive elements of a 1024 chunk
__global__ void k_scanA(const int* __restrict__ cnt, int* __restrict__ rp1,
                        int* __restrict__ bsum) {
    __shared__ int s[256];
    int b = blockIdx.x, t = threadIdx.x;
    int base = b * SCAN_CHUNK + t * 4;
    int v[4], sum = 0;
#pragma unroll
    for (int i = 0; i < 4; i++) {
        v[i] = (base + i < NN) ? cnt[base + i] : 0;
        sum += v[i];
    }
    s[t] = sum;
    __syncthreads();
    for (int off = 1; off < 256; off <<= 1) {
        int x = (t >= off) ? s[t - off] : 0;
        __syncthreads();
        if (t >= off) s[t] += x;
        __syncthreads();
    }
    int run = s[t] - sum;
#pragma unroll
    for (int i = 0; i < 4; i++) {
        run += v[i];
        if (base + i < NN) rp1[base + i] = run;
    }
    if (t == 255) bsum[b] = s[255];
}

__global__ void k_scanB(const int* __restrict__ bsum, int* __restrict__ boff) {
    __shared__ int s[128];
    int t = threadIdx.x;
    int v = (t < SCAN_NB) ? bsum[t] : 0;
    s[t] = v;
    __syncthreads();
    for (int off = 1; off < 128; off <<= 1) {
        int x = (t >= off) ? s[t - off] : 0;
        __syncthreads();
        if (t >= off) s[t] += x;
        __syncthreads();
    }
    if (t < SCAN_NB) boff[t] = s[t] - v;
}

__global__ void k_scanC(const int* __restrict__ rp1, const int* __restrict__ boff,
                        const int* __restrict__ cnt, int* __restrict__ rowptr,
                        int* __restrict__ wptr) {
    int i = blockIdx.x * blockDim.x + threadIdx.x;
    if (i >= NN) return;
    int inc = rp1[i] + boff[i / SCAN_CHUNK];
    rowptr[i + 1] = inc;
    wptr[i] = inc - cnt[i];
    if (i == 0) rowptr[0] = 0;
}

// packed edge record: {src, ea0(bits), ea1(bits), pad} -> one 16B store
__global__ void k_scatter(const int* __restrict__ src, const int* __restrict__ dst,
                          const float* __restrict__ ea, int* __restrict__ wptr,
                          int4* __restrict__ edges) {
    int i = blockIdx.x * blockDim.x + threadIdx.x;
    if (i >= NE) return;
    int d = dst[i];
    int pos = atomicAdd(wptr + d, 1);
    edges[pos] = make_int4(src[i], __float_as_int(ea[2 * i]),
                           __float_as_int(ea[2 * i + 1]), 0);
}

// self-loop mean edge_attr per node: coalesced segmented reduce over CSR
__global__ void k_la(const int* __restrict__ rowptr, const int4* __restrict__ edges,
                     float* __restrict__ la) {
    int n = (blockIdx.x * blockDim.x + threadIdx.x) >> 6;
    if (n >= NN) return;
    int lane = threadIdx.x & 63;
    int s0 = rowptr[n], e0 = rowptr[n + 1];
    float a0 = 0.f, a1 = 0.f;
    for (int e = s0 + lane; e < e0; e += 64) {
        int4 ep = edges[e];
        a0 += __int_as_float(ep.y);
        a1 += __int_as_float(ep.z);
    }
#pragma unroll
    for (int off = 32; off > 0; off >>= 1) {
        a0 += __shfl_xor(a0, off);
        a1 += __shfl_xor(a1, off);
    }
    if (lane == 0) {
        float d = fmaxf((float)(e0 - s0), 1.0f);
        la[2 * n] = a0 / d;
        la[2 * n + 1] = a1 / d;
    }
}

// ---------- dense node transform (layer 2) ----------
template <int IN, int HC>
__global__ void k_nodeh_lds(const float* __restrict__ x, const float* __restrict__ W,
                            float* __restrict__ h) {
    const int NPB = 256 / HC;
    __shared__ float sx[NPB * IN];
    int nb = blockIdx.x * NPB, t = threadIdx.x;
    for (int i = t; i < NPB * IN; i += 256) {
        int node = nb + i / IN;
        sx[i] = (node < NN) ? x[(size_t)node * IN + i % IN] : 0.f;
    }
    __syncthreads();
    int local = t / HC, j = t % HC;
    int node = nb + local;
    if (node >= NN) return;
    float acc = 0.f;
#pragma unroll
    for (int i = 0; i < IN; i++) acc += sx[local * IN + i] * W[i * HC + j];
    h[(size_t)node * HC + j] = acc;
}

// layer-3 transform: wave per node, 64-lane dot product
__global__ void k_nodeh3(const float* __restrict__ x, const float* __restrict__ W,
                         float* __restrict__ h) {
    int wid = (blockIdx.x * blockDim.x + threadIdx.x) >> 6;
    if (wid >= NN) return;
    int lane = threadIdx.x & 63;
    float p = x[(size_t)wid * 64 + lane] * W[lane];
#pragma unroll
    for (int off = 32; off > 0; off >>= 1) p += __shfl_xor(p, off);
    if (lane == 0) h[wid] = p;
}

// ---------- Me[d,h] = sum_c We[d, h*C+c] * aE[h,c] ----------
template <int H, int C>
__global__ void k_me(const float* __restrict__ We, const float* __restrict__ aE,
                     float* __restrict__ me) {
    int t = threadIdx.x;
    if (t >= 2 * H) return;
    int d = t / H, hd = t % H;
    float s = 0.f;
    for (int c = 0; c < C; c++) s += We[d * H * C + hd * C + c] * aE[hd * C + c];
    me[t] = s;
}

// layer-1 prep: vS[hd*5+i] = sum_c W1[i,hd*32+c]*aS1[hd,c] (t<20), vD likewise (t in [20,40))
__global__ void k_vsd(const float* __restrict__ W1, const float* __restrict__ aS1,
                      const float* __restrict__ aD1, float* __restrict__ vsd) {
    int t = threadIdx.x;
    if (t >= 40) return;
    const float* a = (t < 20) ? aS1 : aD1;
    int r = t % 20, hd = r / 5, i = r % 5;
    float s = 0.f;
    for (int c = 0; c < 32; c++) s += W1[i * 128 + hd * 32 + c] * a[hd * 32 + c];
    vsd[t] = s;
}

// ---------- per-node attention coefficients (layers 2,3) ----------
template <int H, int C>
__global__ void k_al(const float* __restrict__ h, const float* __restrict__ aS,
                     const float* __restrict__ aD, float* __restrict__ als,
                     float* __restrict__ ald) {
    int t = blockIdx.x * blockDim.x + threadIdx.x;
    if (t >= NN * H) return;
    int n = t / H, hd = t % H;
    const float* hr = h + (size_t)n * H * C + hd * C;
    float s1 = 0.f, s2 = 0.f;
#pragma unroll
    for (int c = 0; c < C; c++) {
        float v = hr[c];
        s1 += v * aS[hd * C + c];
        s2 += v * aD[hd * C + c];
    }
    als[t] = s1;
    ald[t] = s2;
}

// ---------- layer 1 fully fused: h1/als/ald computed on the fly from x ----------
__global__ void k_agg1(const int* __restrict__ rowptr, const int4* __restrict__ edges,
                       const float* __restrict__ x, const float* __restrict__ W1,
                       const float* __restrict__ vsd, const float* __restrict__ la,
                       const float* __restrict__ me, const float* __restrict__ b,
                       float* __restrict__ out) {
    int n = (blockIdx.x * blockDim.x + threadIdx.x) >> 6;
    if (n >= NN) return;
    int lane = threadIdx.x & 63;
    float xn[5];
#pragma unroll
    for (int i = 0; i < 5; i++) xn[i] = x[(size_t)n * 5 + i];
    float la0 = la[2 * n], la1 = la[2 * n + 1];
    int start = rowptr[n], end = rowptr[n + 1];
    float m[2], den[2], acc[2], me0[2], me1[2], aldk[2], bk[2], vSk[2][5], wc[2][5];
    int ch[2];
#pragma unroll
    for (int k = 0; k < 2; k++) {
        ch[k] = lane + 64 * k;
        int hd = ch[k] >> 5;
        me0[k] = me[hd];
        me1[k] = me[4 + hd];
        bk[k] = b[ch[k]];
        float ad = 0.f, as = 0.f, hs = 0.f;
#pragma unroll
        for (int i = 0; i < 5; i++) {
            vSk[k][i] = vsd[hd * 5 + i];
            wc[k][i] = W1[i * 128 + ch[k]];
            ad += xn[i] * vsd[20 + hd * 5 + i];
            as += xn[i] * vSk[k][i];
            hs += xn[i] * wc[k][i];
        }
        aldk[k] = ad;
        float aself = lrelu(as + ad + la0 * me0[k] + la1 * me1[k]);
        m[k] = aself;
        den[k] = 1.f;
        acc[k] = hs;  // * exp(aself - m) = 1
    }
    for (int e = start; e < end; ++e) {
        int4 ep = edges[e];
        int s = ep.x;
        float ea0 = __int_as_float(ep.y), ea1 = __int_as_float(ep.z);
        float xs[5];
#pragma unroll
        for (int i = 0; i < 5; i++) xs[i] = x[(size_t)s * 5 + i];
#pragma unroll
        for (int k = 0; k < 2; k++) {
            float as = 0.f, hv = 0.f;
#pragma unroll
            for (int i = 0; i < 5; i++) {
                as += xs[i] * vSk[k][i];
                hv += xs[i] * wc[k][i];
            }
            float a = lrelu(as + aldk[k] + ea0 * me0[k] + ea1 * me1[k]);
            float mn = fmaxf(m[k], a);
            float sc = __expf(m[k] - mn);
            float p  = __expf(a - mn);
            den[k] = den[k] * sc + p;
            acc[k] = acc[k] * sc + p * hv;
            m[k] = mn;
        }
    }
#pragma unroll
    for (int k = 0; k < 2; k++)
        out[(size_t)n * 128 + ch[k]] = elu1(acc[k] / den[k] + bk[k]);
}

// ---------- generic fused aggregation (layer 2): online softmax, wave per node ----------
template <int H, int C, int K>
__global__ void k_agg(const int* __restrict__ rowptr, const int4* __restrict__ edges,
                      const float* __restrict__ h, const float* __restrict__ als,
                      const float* __restrict__ ald, const float* __restrict__ la,
                      const float* __restrict__ me, const float* __restrict__ b,
                      float* __restrict__ out) {
    const int HC = 64 * K;
    int n = (blockIdx.x * blockDim.x + threadIdx.x) >> 6;
    if (n >= NN) return;
    int lane = threadIdx.x & 63;
    float la0 = la[2 * n], la1 = la[2 * n + 1];
    int start = rowptr[n], end = rowptr[n + 1];
    float m[K], den[K], acc[K], me0[K], me1[K], aldk[K], bk[K];
    int hd[K], ch[K];
#pragma unroll
    for (int k = 0; k < K; k++) {
        ch[k] = lane + 64 * k;
        hd[k] = ch[k] / C;
        me0[k] = me[hd[k]];
        me1[k] = me[H + hd[k]];
        aldk[k] = ald[n * H + hd[k]];
        float aself = lrelu(als[n * H + hd[k]] + aldk[k] + la0 * me0[k] + la1 * me1[k]);
        m[k] = aself;
        den[k] = 1.f;
        acc[k] = h[(size_t)n * HC + ch[k]];
        bk[k] = b[ch[k]];
    }
    for (int e = start; e < end; ++e) {
        int4 ep = edges[e];
        int s = ep.x;
        float ea0 = __int_as_float(ep.y), ea1 = __int_as_float(ep.z);
        size_t hb = (size_t)s * HC;
#pragma unroll
        for (int k = 0; k < K; k++) {
            float a = lrelu(als[s * H + hd[k]] + aldk[k] + ea0 * me0[k] + ea1 * me1[k]);
            float hv = h[hb + ch[k]];
            float mn = fmaxf(m[k], a);
            float sc = __expf(m[k] - mn);
            float p  = __expf(a - mn);
            den[k] = den[k] * sc + p;
            acc[k] = acc[k] * sc + p * hv;
            m[k] = mn;
        }
    }
#pragma unroll
    for (int k = 0; k < K; k++) {
        float v = acc[k] / den[k] + bk[k];
        out[(size_t)n * HC + ch[k]] = elu1(v);
    }
}

// ---------- layer 3: H=1,C=1; wave per node, lanes parallel over edges ----------
__global__ void k_agg3(const int* __restrict__ rowptr, const int4* __restrict__ edges,
                       const float* __restrict__ h, const float* __restrict__ als,
                       const float* __restrict__ ald, const float* __restrict__ la,
                       const float* __restrict__ me, const float* __restrict__ b,
                       float* __restrict__ out) {
    int n = (blockIdx.x * blockDim.x + threadIdx.x) >> 6;
    if (n >= NN) return;
    int lane = threadIdx.x & 63;
    float me0 = me[0], me1 = me[1];
    float ald_n = ald[n];
    int start = rowptr[n], end = rowptr[n + 1];
    float m = -1e30f, den = 0.f, num = 0.f;
    for (int e = start + lane; e < end; e += 64) {
        int4 ep = edges[e];
        int s = ep.x;
        float a = lrelu(als[s] + ald_n + __int_as_float(ep.y) * me0 +
                        __int_as_float(ep.z) * me1);
        float hv = h[s];
        float mn = fmaxf(m, a);
        float sc = __expf(m - mn);
        float p  = __expf(a - mn);
        den = den * sc + p;
        num = num * sc + p * hv;
        m = mn;
    }
#pragma unroll
    for (int off = 1; off < 64; off <<= 1) {
        float mo = __shfl_xor(m, off);
        float dn = __shfl_xor(den, off);
        float nm = __shfl_xor(num, off);
        float mn = fmaxf(m, mo);
        float s1 = __expf(m - mn), s2 = __expf(mo - mn);
        den = den * s1 + dn * s2;
        num = num * s1 + nm * s2;
        m = mn;
    }
    if (lane == 0) {
        float aself = lrelu(als[n] + ald_n + la[2 * n] * me0 + la[2 * n + 1] * me1);
        float mn = fmaxf(m, aself);
        float sc = __expf(m - mn), ws = __expf(aself - mn);
        den = den * sc + ws;
        num = num * sc + ws * h[n];
        float v = num / den + b[0];
        out[n] = 1.f / (1.f + __expf(-v));
    }
}

extern "C" void kernel_launch(void* const* d_in, const int* in_sizes, int n_in,
                              void* d_out, int out_size, void* d_ws, size_t ws_size,
                              hipStream_t stream) {
    const float* x   = (const float*)d_in[0];
    const int*   ei  = (const int*)d_in[1];
    const float* ea  = (const float*)d_in[2];
    const float* W1  = (const float*)d_in[3];
    const float* aS1 = (const float*)d_in[4];
    const float* aD1 = (const float*)d_in[5];
    const float* We1 = (const float*)d_in[6];
    const float* aE1 = (const float*)d_in[7];
    const float* b1  = (const float*)d_in[8];
    const float* W2  = (const float*)d_in[9];
    const float* aS2 = (const float*)d_in[10];
    const float* aD2 = (const float*)d_in[11];
    const float* We2 = (const float*)d_in[12];
    const float* aE2 = (const float*)d_in[13];
    const float* b2  = (const float*)d_in[14];
    const float* W3  = (const float*)d_in[15];
    const float* aS3 = (const float*)d_in[16];
    const float* aD3 = (const float*)d_in[17];
    const float* We3 = (const float*)d_in[18];
    const float* aE3 = (const float*)d_in[19];
    const float* b3  = (const float*)d_in[20];

    const int* srcv = ei;
    const int* dstv = ei + NE;

    char* basep = (char*)d_ws;
    size_t off = 0;
    auto alloc = [&](size_t nbytes) -> void* {
        void* p = basep + off;
        off += (nbytes + 255) & ~(size_t)255;
        return p;
    };
    int*    cnt    = (int*)alloc((size_t)NN * 4);
    float*  la     = (float*)alloc((size_t)NN * 8);
    int*    rp1    = (int*)alloc((size_t)NN * 4);
    int*    rowptr = (int*)alloc((size_t)(NN + 1) * 4);
    int*    wptr   = (int*)alloc((size_t)NN * 4);
    int*    bsum   = (int*)alloc(512);
    int*    boff   = (int*)alloc(512);
    int4*   edges  = (int4*)alloc((size_t)NE * 16);
    float*  me     = (float*)alloc(256);
    float*  vsd    = (float*)alloc(256);
    float*  als    = (float*)alloc((size_t)NN * 16);
    float*  ald    = (float*)alloc((size_t)NN * 16);
    float*  A      = (float*)alloc((size_t)NN * 128 * 4);
    float*  B      = (float*)alloc((size_t)NN * 128 * 4);
    float*  h3     = (float*)alloc((size_t)NN * 4);
    (void)ws_size; (void)in_sizes; (void)n_in; (void)out_size;

    auto cdiv = [](long long a, long long b) { return (int)((a + b - 1) / b); };
    const int BS = 256;

    // ---- CSR build (once per call; reused by all 3 layers) ----
    hipMemsetAsync(cnt, 0, (size_t)NN * 4, stream);
    k_count<<<cdiv(NE, BS), BS, 0, stream>>>(dstv, cnt);
    k_scanA<<<SCAN_NB, 256, 0, stream>>>(cnt, rp1, bsum);
    k_scanB<<<1, 128, 0, stream>>>(bsum, boff);
    k_scanC<<<cdiv(NN, BS), BS, 0, stream>>>(rp1, boff, cnt, rowptr, wptr);
    k_scatter<<<cdiv(NE, BS), BS, 0, stream>>>(srcv, dstv, ea, wptr, edges);
    k_la<<<cdiv(NN, 4), 256, 0, stream>>>(rowptr, edges, la);

    // ================= Layer 1: IN=5, H=4, C=32 (ELU), fully fused =================
    k_me<4, 32><<<1, 64, 0, stream>>>(We1, aE1, me);
    k_vsd<<<1, 64, 0, stream>>>(W1, aS1, aD1, vsd);
    k_agg1<<<cdiv(NN, 4), 256, 0, stream>>>(rowptr, edges, x, W1, vsd, la, me, b1, B);

    // ================= Layer 2: IN=128, H=2, C=32 (ELU) =================
    k_nodeh_lds<128, 64><<<cdiv(NN, 4), 256, 0, stream>>>(B, W2, A);  // h2 -> A
    k_me<2, 32><<<1, 64, 0, stream>>>(We2, aE2, me);
    k_al<2, 32><<<cdiv((long long)NN * 2, BS), BS, 0, stream>>>(A, aS2, aD2, als, ald);
    k_agg<2, 32, 1><<<cdiv(NN, 4), 256, 0, stream>>>(rowptr, edges, A, als, ald,
                                                     la, me, b2, B);  // act2 -> B

    // ================= Layer 3: IN=64, H=1, C=1 (sigmoid) =================
    k_nodeh3<<<cdiv(NN, 4), 256, 0, stream>>>(B, W3, h3);
    k_me<1, 1><<<1, 64, 0, stream>>>(We3, aE3, me);
    k_al<1, 1><<<cdiv(NN, BS), BS, 0, stream>>>(h3, aS3, aD3, als, ald);
    k_agg3<<<cdiv(NN, 4), 256, 0, stream>>>(rowptr, edges, h3, als, ald, la, me,
                                            b3, (float*)d_out);
}

// Round 4
// 738.162 us; speedup vs baseline: 23.9006x; 1.1784x over previous
//
#include <hip/hip_runtime.h>
#include <math.h>

#define NN 100000
#define NE 1600000
#define SCAN_CHUNK 1024
#define SCAN_NB ((NN + SCAN_CHUNK - 1) / SCAN_CHUNK)  // 98
#define LOG2E 1.44269504088896f

__device__ __forceinline__ float lrelu(float x) { return fmaxf(x, 0.2f * x); }
__device__ __forceinline__ float elu1(float x) { return x > 0.f ? x : (__expf(x) - 1.f); }
__device__ __forceinline__ float fexp2(float x) {
#if __has_builtin(__builtin_amdgcn_exp2f)
    return __builtin_amdgcn_exp2f(x);
#else
    return exp2f(x);
#endif
}

// ---------- CSR build ----------
__global__ void k_count(const int* __restrict__ dst, int* __restrict__ cnt) {
    int i = blockIdx.x * blockDim.x + threadIdx.x;
    if (i >= NE) return;
    atomicAdd(cnt + dst[i], 1);
}

__global__ void k_scanA(const int* __restrict__ cnt, int* __restrict__ rp1,
                        int* __restrict__ bsum) {
    __shared__ int s[256];
    int b = blockIdx.x, t = threadIdx.x;
    int base = b * SCAN_CHUNK + t * 4;
    int v[4], sum = 0;
#pragma unroll
    for (int i = 0; i < 4; i++) {
        v[i] = (base + i < NN) ? cnt[base + i] : 0;
        sum += v[i];
    }
    s[t] = sum;
    __syncthreads();
    for (int off = 1; off < 256; off <<= 1) {
        int x = (t >= off) ? s[t - off] : 0;
        __syncthreads();
        if (t >= off) s[t] += x;
        __syncthreads();
    }
    int run = s[t] - sum;
#pragma unroll
    for (int i = 0; i < 4; i++) {
        run += v[i];
        if (base + i < NN) rp1[base + i] = run;
    }
    if (t == 255) bsum[b] = s[255];
}

__global__ void k_scanB(const int* __restrict__ bsum, int* __restrict__ boff) {
    __shared__ int s[128];
    int t = threadIdx.x;
    int v = (t < SCAN_NB) ? bsum[t] : 0;
    s[t] = v;
    __syncthreads();
    for (int off = 1; off < 128; off <<= 1) {
        int x = (t >= off) ? s[t - off] : 0;
        __syncthreads();
        if (t >= off) s[t] += x;
        __syncthreads();
    }
    if (t < SCAN_NB) boff[t] = s[t] - v;
}

__global__ void k_scanC(const int* __restrict__ rp1, const int* __restrict__ boff,
                        const int* __restrict__ cnt, int* __restrict__ rowptr,
                        int* __restrict__ wptr) {
    int i = blockIdx.x * blockDim.x + threadIdx.x;
    if (i >= NN) return;
    int inc = rp1[i] + boff[i / SCAN_CHUNK];
    rowptr[i + 1] = inc;
    wptr[i] = inc - cnt[i];
    if (i == 0) rowptr[0] = 0;
}

__global__ void k_scatter(const int* __restrict__ src, const int* __restrict__ dst,
                          const float* __restrict__ ea, int* __restrict__ wptr,
                          int4* __restrict__ edges) {
    int i = blockIdx.x * blockDim.x + threadIdx.x;
    if (i >= NE) return;
    int d = dst[i];
    int pos = atomicAdd(wptr + d, 1);
    edges[pos] = make_int4(src[i], __float_as_int(ea[2 * i]),
                           __float_as_int(ea[2 * i + 1]), 0);
}

// self-loop mean edge_attr per node
__global__ void k_la(const int* __restrict__ rowptr, const int4* __restrict__ edges,
                     float* __restrict__ la) {
    int n = (blockIdx.x * blockDim.x + threadIdx.x) >> 6;
    if (n >= NN) return;
    int lane = threadIdx.x & 63;
    int s0 = rowptr[n], e0 = rowptr[n + 1];
    float a0 = 0.f, a1 = 0.f;
    for (int e = s0 + lane; e < e0; e += 64) {
        int4 ep = edges[e];
        a0 += __int_as_float(ep.y);
        a1 += __int_as_float(ep.z);
    }
#pragma unroll
    for (int off = 32; off > 0; off >>= 1) {
        a0 += __shfl_xor(a0, off);
        a1 += __shfl_xor(a1, off);
    }
    if (lane == 0) {
        float d = fmaxf((float)(e0 - s0), 1.0f);
        la[2 * n] = a0 / d;
        la[2 * n + 1] = a1 / d;
    }
}

// ---------- x padded to 8 floats/node (two aligned float4) ----------
__global__ void k_xpad(const float* __restrict__ x, float4* __restrict__ xp) {
    int t = blockIdx.x * blockDim.x + threadIdx.x;
    if (t >= NN * 2) return;
    int n = t >> 1;
    float4 v;
    if ((t & 1) == 0)
        v = make_float4(x[n * 5], x[n * 5 + 1], x[n * 5 + 2], x[n * 5 + 3]);
    else
        v = make_float4(x[n * 5 + 4], 0.f, 0.f, 0.f);
    xp[t] = v;
}

// ---------- Me[d,h] scaled by LOG2E ----------
template <int H, int C>
__global__ void k_me(const float* __restrict__ We, const float* __restrict__ aE,
                     float* __restrict__ me) {
    int t = threadIdx.x;
    if (t >= 2 * H) return;
    int d = t / H, hd = t % H;
    float s = 0.f;
    for (int c = 0; c < C; c++) s += We[d * H * C + hd * C + c] * aE[hd * C + c];
    me[t] = s * LOG2E;
}

// layer-1 prep: vS/vD (scaled by LOG2E)
__global__ void k_vsd(const float* __restrict__ W1, const float* __restrict__ aS1,
                      const float* __restrict__ aD1, float* __restrict__ vsd) {
    int t = threadIdx.x;
    if (t >= 40) return;
    const float* a = (t < 20) ? aS1 : aD1;
    int r = t % 20, hd = r / 5, i = r % 5;
    float s = 0.f;
    for (int c = 0; c < 32; c++) s += W1[i * 128 + hd * 32 + c] * a[hd * 32 + c];
    vsd[t] = s * LOG2E;
}

// layer-1 per-node logits (scaled): als1/ald1[NN*4]
__global__ void k_al1(const float4* __restrict__ xp, const float* __restrict__ vsd,
                      float* __restrict__ als1, float* __restrict__ ald1) {
    int t = blockIdx.x * blockDim.x + threadIdx.x;
    if (t >= NN * 4) return;
    int n = t >> 2, hd = t & 3;
    float4 xa = xp[n * 2], xb = xp[n * 2 + 1];
    const float* vS = vsd + hd * 5;
    const float* vD = vsd + 20 + hd * 5;
    als1[t] = xa.x * vS[0] + xa.y * vS[1] + xa.z * vS[2] + xa.w * vS[3] + xb.x * vS[4];
    ald1[t] = xa.x * vD[0] + xa.y * vD[1] + xa.z * vD[2] + xa.w * vD[3] + xb.x * vD[4];
}

// ---------- layer 1 fused agg: wave per node, lane = 2 adjacent channels, 1 head ----------
__global__ void k_agg1(const int* __restrict__ rowptr, const int4* __restrict__ edges,
                       const float4* __restrict__ xp, const float* __restrict__ W1,
                       const float* __restrict__ als1, const float* __restrict__ ald1,
                       const float* __restrict__ la, const float* __restrict__ me,
                       const float* __restrict__ b, float* __restrict__ out) {
    int n = (blockIdx.x * blockDim.x + threadIdx.x) >> 6;
    if (n >= NN) return;
    int lane = threadIdx.x & 63;
    int c0 = 2 * lane;       // channels c0, c0+1
    int hd = lane >> 4;      // head = c0/32
    float me0 = me[hd], me1 = me[4 + hd];
    float aldn = ald1[n * 4 + hd];
    float alsn = als1[n * 4 + hd];
    float la0 = la[2 * n], la1 = la[2 * n + 1];
    float w0[5], w1[5];
#pragma unroll
    for (int i = 0; i < 5; i++) {
        w0[i] = W1[i * 128 + c0];
        w1[i] = W1[i * 128 + c0 + 1];
    }
    float4 xa = xp[n * 2], xb = xp[n * 2 + 1];
    float hs0 = xa.x * w0[0] + xa.y * w0[1] + xa.z * w0[2] + xa.w * w0[3] + xb.x * w0[4];
    float hs1 = xa.x * w1[0] + xa.y * w1[1] + xa.z * w1[2] + xa.w * w1[3] + xb.x * w1[4];
    float aself = lrelu(alsn + aldn + la0 * me0 + la1 * me1);
    float m = aself, den = 1.f, acc0 = hs0, acc1 = hs1;
    int start = rowptr[n], end = rowptr[n + 1];
    for (int e = start; e < end; ++e) {
        int4 ep = edges[e];
        int s = ep.x;
        float asv = als1[s * 4 + hd];
        float4 sa = xp[s * 2], sb = xp[s * 2 + 1];
        float a = asv + aldn + __int_as_float(ep.y) * me0 + __int_as_float(ep.z) * me1;
        a = lrelu(a);
        float hv0 = sa.x * w0[0] + sa.y * w0[1] + sa.z * w0[2] + sa.w * w0[3] + sb.x * w0[4];
        float hv1 = sa.x * w1[0] + sa.y * w1[1] + sa.z * w1[2] + sa.w * w1[3] + sb.x * w1[4];
        float mn = fmaxf(m, a);
        float ex = fexp2(-fabsf(a - m));
        bool gt = a > m;
        float sc = gt ? ex : 1.f;
        float p  = gt ? 1.f : ex;
        den  = den * sc + p;
        acc0 = acc0 * sc + p * hv0;
        acc1 = acc1 * sc + p * hv1;
        m = mn;
    }
    float r0 = elu1(acc0 / den + b[c0]);
    float r1 = elu1(acc1 / den + b[c0 + 1]);
    *(float2*)(out + (size_t)n * 128 + c0) = make_float2(r0, r1);
}

// ---------- layer 2 dense transform + fused als/ald (scaled) ----------
__global__ void k_nodeh2(const float* __restrict__ x, const float* __restrict__ W,
                         const float* __restrict__ aS, const float* __restrict__ aD,
                         float* __restrict__ h, float* __restrict__ als,
                         float* __restrict__ ald) {
    __shared__ float sx[4 * 128];
    int nb = blockIdx.x * 4, t = threadIdx.x;
    for (int i = t; i < 4 * 128; i += 256) {
        int node = nb + (i >> 7);
        sx[i] = (node < NN) ? x[(size_t)node * 128 + (i & 127)] : 0.f;
    }
    __syncthreads();
    int local = t >> 6, j = t & 63;
    int node = nb + local;
    float acc = 0.f;
#pragma unroll
    for (int i = 0; i < 128; i++) acc += sx[local * 128 + i] * W[i * 64 + j];
    float pS = acc * aS[j], pD = acc * aD[j];
#pragma unroll
    for (int off = 16; off > 0; off >>= 1) {
        pS += __shfl_xor(pS, off);
        pD += __shfl_xor(pD, off);
    }
    if (node < NN) {
        h[(size_t)node * 64 + j] = acc;
        if ((j & 31) == 0) {
            int hd = j >> 5;
            als[node * 2 + hd] = pS * LOG2E;
            ald[node * 2 + hd] = pD * LOG2E;
        }
    }
}

// ---------- layer 2 agg: 2 nodes per wave, 32 lanes/node, 2 ch/lane ----------
__global__ void k_agg2(const int* __restrict__ rowptr, const int4* __restrict__ edges,
                       const float* __restrict__ h, const float* __restrict__ als,
                       const float* __restrict__ ald, const float* __restrict__ la,
                       const float* __restrict__ me, const float* __restrict__ b,
                       float* __restrict__ out) {
    int w = (blockIdx.x * blockDim.x + threadIdx.x) >> 6;
    if (w >= NN / 2) return;
    int half = (threadIdx.x >> 5) & 1;
    int n = 2 * w + half;
    int lane = threadIdx.x & 31;
    int c0 = 2 * lane;       // channels c0, c0+1 of node n
    int hd = lane >> 4;      // c0/32
    float me0 = me[hd], me1 = me[2 + hd];
    float aldn = ald[n * 2 + hd];
    float alsn = als[n * 2 + hd];
    float la0 = la[2 * n], la1 = la[2 * n + 1];
    float2 hn = *(const float2*)(h + (size_t)n * 64 + c0);
    float aself = lrelu(alsn + aldn + la0 * me0 + la1 * me1);
    float m = aself, den = 1.f, acc0 = hn.x, acc1 = hn.y;
    int start = rowptr[n], end = rowptr[n + 1];
    for (int e = start; e < end; ++e) {
        int4 ep = edges[e];
        int s = ep.x;
        float asv = als[s * 2 + hd];
        float2 hv = *(const float2*)(h + (size_t)s * 64 + c0);
        float a = asv + aldn + __int_as_float(ep.y) * me0 + __int_as_float(ep.z) * me1;
        a = lrelu(a);
        float mn = fmaxf(m, a);
        float ex = fexp2(-fabsf(a - m));
        bool gt = a > m;
        float sc = gt ? ex : 1.f;
        float p  = gt ? 1.f : ex;
        den  = den * sc + p;
        acc0 = acc0 * sc + p * hv.x;
        acc1 = acc1 * sc + p * hv.y;
        m = mn;
    }
    float r0 = elu1(acc0 / den + b[c0]);
    float r1 = elu1(acc1 / den + b[c0 + 1]);
    *(float2*)(out + (size_t)n * 64 + c0) = make_float2(r0, r1);
}

// ---------- layer 3 transform: wave per node, 64-lane dot ----------
__global__ void k_nodeh3(const float* __restrict__ x, const float* __restrict__ W,
                         float* __restrict__ h) {
    int wid = (blockIdx.x * blockDim.x + threadIdx.x) >> 6;
    if (wid >= NN) return;
    int lane = threadIdx.x & 63;
    float p = x[(size_t)wid * 64 + lane] * W[lane];
#pragma unroll
    for (int off = 32; off > 0; off >>= 1) p += __shfl_xor(p, off);
    if (lane == 0) h[wid] = p;
}

// ---------- layer 3 agg: H=1,C=1; lanes parallel over edges ----------
__global__ void k_agg3(const int* __restrict__ rowptr, const int4* __restrict__ edges,
                       const float* __restrict__ h, const float* __restrict__ aS3,
                       const float* __restrict__ aD3, const float* __restrict__ la,
                       const float* __restrict__ me, const float* __restrict__ b,
                       float* __restrict__ out) {
    int n = (blockIdx.x * blockDim.x + threadIdx.x) >> 6;
    if (n >= NN) return;
    int lane = threadIdx.x & 63;
    float me0 = me[0], me1 = me[1];
    float aSs = aS3[0] * LOG2E, aDs = aD3[0] * LOG2E;
    float hn = h[n];
    float ald_n = hn * aDs;
    int start = rowptr[n], end = rowptr[n + 1];
    float m = -1e30f, den = 0.f, num = 0.f;
    for (int e = start + lane; e < end; e += 64) {
        int4 ep = edges[e];
        int s = ep.x;
        float hv = h[s];
        float a = lrelu(hv * aSs + ald_n + __int_as_float(ep.y) * me0 +
                        __int_as_float(ep.z) * me1);
        float mn = fmaxf(m, a);
        float ex = fexp2(-fabsf(a - m));
        bool gt = a > m;
        float sc = gt ? ex : 1.f;
        float p  = gt ? 1.f : ex;
        den = den * sc + p;
        num = num * sc + p * hv;
        m = mn;
    }
#pragma unroll
    for (int off = 1; off < 64; off <<= 1) {
        float mo = __shfl_xor(m, off);
        float dn = __shfl_xor(den, off);
        float nm = __shfl_xor(num, off);
        float ex = fexp2(-fabsf(m - mo));
        bool gt = mo > m;
        float s1 = gt ? ex : 1.f;
        float s2 = gt ? 1.f : ex;
        den = den * s1 + dn * s2;
        num = num * s1 + nm * s2;
        m = fmaxf(m, mo);
    }
    if (lane == 0) {
        float aself = lrelu(hn * aSs + ald_n + la[2 * n] * me0 + la[2 * n + 1] * me1);
        float ex = fexp2(-fabsf(aself - m));
        bool gt = aself > m;
        float sc = gt ? ex : 1.f;
        float p  = gt ? 1.f : ex;
        den = den * sc + p;
        num = num * sc + p * hn;
        float v = num / den + b[0];
        out[n] = 1.f / (1.f + __expf(-v));
    }
}

extern "C" void kernel_launch(void* const* d_in, const int* in_sizes, int n_in,
                              void* d_out, int out_size, void* d_ws, size_t ws_size,
                              hipStream_t stream) {
    const float* x   = (const float*)d_in[0];
    const int*   ei  = (const int*)d_in[1];
    const float* ea  = (const float*)d_in[2];
    const float* W1  = (const float*)d_in[3];
    const float* aS1 = (const float*)d_in[4];
    const float* aD1 = (const float*)d_in[5];
    const float* We1 = (const float*)d_in[6];
    const float* aE1 = (const float*)d_in[7];
    const float* b1  = (const float*)d_in[8];
    const float* W2  = (const float*)d_in[9];
    const float* aS2 = (const float*)d_in[10];
    const float* aD2 = (const float*)d_in[11];
    const float* We2 = (const float*)d_in[12];
    const float* aE2 = (const float*)d_in[13];
    const float* b2  = (const float*)d_in[14];
    const float* W3  = (const float*)d_in[15];
    const float* aS3 = (const float*)d_in[16];
    const float* aD3 = (const float*)d_in[17];
    const float* We3 = (const float*)d_in[18];
    const float* aE3 = (const float*)d_in[19];
    const float* b3  = (const float*)d_in[20];

    const int* srcv = ei;
    const int* dstv = ei + NE;

    char* basep = (char*)d_ws;
    size_t off = 0;
    auto alloc = [&](size_t nbytes) -> void* {
        void* p = basep + off;
        off += (nbytes + 255) & ~(size_t)255;
        return p;
    };
    int*    cnt    = (int*)alloc((size_t)NN * 4);
    float*  la     = (float*)alloc((size_t)NN * 8);
    int*    rp1    = (int*)alloc((size_t)NN * 4);
    int*    rowptr = (int*)alloc((size_t)(NN + 1) * 4);
    int*    wptr   = (int*)alloc((size_t)NN * 4);
    int*    bsum   = (int*)alloc(512);
    int*    boff   = (int*)alloc(512);
    int4*   edges  = (int4*)alloc((size_t)NE * 16);
    float*  me     = (float*)alloc(256);
    float*  vsd    = (float*)alloc(256);
    float4* xp     = (float4*)alloc((size_t)NN * 32);
    float*  als1   = (float*)alloc((size_t)NN * 16);
    float*  ald1   = (float*)alloc((size_t)NN * 16);
    float*  als2   = (float*)alloc((size_t)NN * 8);
    float*  ald2   = (float*)alloc((size_t)NN * 8);
    float*  A      = (float*)alloc((size_t)NN * 128 * 4);
    float*  B      = (float*)alloc((size_t)NN * 128 * 4);
    float*  h3     = (float*)alloc((size_t)NN * 4);
    (void)ws_size; (void)in_sizes; (void)n_in; (void)out_size;

    auto cdiv = [](long long a, long long b) { return (int)((a + b - 1) / b); };
    const int BS = 256;

    // ---- CSR build ----
    hipMemsetAsync(cnt, 0, (size_t)NN * 4, stream);
    k_count<<<cdiv(NE, BS), BS, 0, stream>>>(dstv, cnt);
    k_scanA<<<SCAN_NB, 256, 0, stream>>>(cnt, rp1, bsum);
    k_scanB<<<1, 128, 0, stream>>>(bsum, boff);
    k_scanC<<<cdiv(NN, BS), BS, 0, stream>>>(rp1, boff, cnt, rowptr, wptr);
    k_scatter<<<cdiv(NE, BS), BS, 0, stream>>>(srcv, dstv, ea, wptr, edges);
    k_la<<<cdiv(NN, 4), 256, 0, stream>>>(rowptr, edges, la);
    k_xpad<<<cdiv((long long)NN * 2, BS), BS, 0, stream>>>(x, xp);

    // ================= Layer 1: IN=5, H=4, C=32 (ELU) =================
    k_me<4, 32><<<1, 64, 0, stream>>>(We1, aE1, me);
    k_vsd<<<1, 64, 0, stream>>>(W1, aS1, aD1, vsd);
    k_al1<<<cdiv((long long)NN * 4, BS), BS, 0, stream>>>(xp, vsd, als1, ald1);
    k_agg1<<<cdiv((long long)NN * 64, BS), BS, 0, stream>>>(rowptr, edges, xp, W1,
                                                            als1, ald1, la, me, b1, B);

    // ================= Layer 2: IN=128, H=2, C=32 (ELU) =================
    k_nodeh2<<<cdiv(NN, 4), 256, 0, stream>>>(B, W2, aS2, aD2, A, als2, ald2);
    k_me<2, 32><<<1, 64, 0, stream>>>(We2, aE2, me);
    k_agg2<<<cdiv((long long)(NN / 2) * 64, BS), BS, 0, stream>>>(rowptr, edges, A, als2,
                                                                  ald2, la, me, b2, B);

    // ================= Layer 3: IN=64, H=1, C=1 (sigmoid) =================
    k_nodeh3<<<cdiv(NN, 4), 256, 0, stream>>>(B, W3, h3);
    k_me<1, 1><<<1, 64, 0, stream>>>(We3, aE3, me);
    k_agg3<<<cdiv(NN, 4), 256, 0, stream>>>(rowptr, edges, h3, aS3, aD3, la, me,
                                            b3, (float*)d_out);
}

// Round 5
// 610.769 us; speedup vs baseline: 28.8857x; 1.2086x over previous
//
#include <hip/hip_runtime.h>
#include <math.h>

#define NN 100000
#define NE 1600000
#define SCAN_CHUNK 1024
#define SCAN_NB ((NN + SCAN_CHUNK - 1) / SCAN_CHUNK)  // 98
#define LOG2E 1.44269504088896f

__device__ __forceinline__ float lrelu(float x) { return fmaxf(x, 0.2f * x); }
__device__ __forceinline__ float elu1(float x) { return x > 0.f ? x : (__expf(x) - 1.f); }
__device__ __forceinline__ float fexp2(float x) {
#if __has_builtin(__builtin_amdgcn_exp2f)
    return __builtin_amdgcn_exp2f(x);
#else
    return exp2f(x);
#endif
}

// ---------- CSR build ----------
__global__ void k_count(const int* __restrict__ dst, int* __restrict__ cnt) {
    int i = blockIdx.x * blockDim.x + threadIdx.x;
    if (i >= NE) return;
    atomicAdd(cnt + dst[i], 1);
}

__global__ void k_scanA(const int* __restrict__ cnt, int* __restrict__ rp1,
                        int* __restrict__ bsum) {
    __shared__ int s[256];
    int b = blockIdx.x, t = threadIdx.x;
    int base = b * SCAN_CHUNK + t * 4;
    int v[4], sum = 0;
#pragma unroll
    for (int i = 0; i < 4; i++) {
        v[i] = (base + i < NN) ? cnt[base + i] : 0;
        sum += v[i];
    }
    s[t] = sum;
    __syncthreads();
    for (int off = 1; off < 256; off <<= 1) {
        int x = (t >= off) ? s[t - off] : 0;
        __syncthreads();
        if (t >= off) s[t] += x;
        __syncthreads();
    }
    int run = s[t] - sum;
#pragma unroll
    for (int i = 0; i < 4; i++) {
        run += v[i];
        if (base + i < NN) rp1[base + i] = run;
    }
    if (t == 255) bsum[b] = s[255];
}

__global__ void k_scanB(const int* __restrict__ bsum, int* __restrict__ boff) {
    __shared__ int s[128];
    int t = threadIdx.x;
    int v = (t < SCAN_NB) ? bsum[t] : 0;
    s[t] = v;
    __syncthreads();
    for (int off = 1; off < 128; off <<= 1) {
        int x = (t >= off) ? s[t - off] : 0;
        __syncthreads();
        if (t >= off) s[t] += x;
        __syncthreads();
    }
    if (t < SCAN_NB) boff[t] = s[t] - v;
}

__global__ void k_scanC(const int* __restrict__ rp1, const int* __restrict__ boff,
                        const int* __restrict__ cnt, int* __restrict__ rowptr,
                        int* __restrict__ wptr) {
    int i = blockIdx.x * blockDim.x + threadIdx.x;
    if (i >= NN) return;
    int inc = rp1[i] + boff[i / SCAN_CHUNK];
    rowptr[i + 1] = inc;
    wptr[i] = inc - cnt[i];
    if (i == 0) rowptr[0] = 0;
}

__global__ void k_scatter(const int* __restrict__ src, const int* __restrict__ dst,
                          const float* __restrict__ ea, int* __restrict__ wptr,
                          int4* __restrict__ edges) {
    int i = blockIdx.x * blockDim.x + threadIdx.x;
    if (i >= NE) return;
    int d = dst[i];
    int pos = atomicAdd(wptr + d, 1);
    edges[pos] = make_int4(src[i], __float_as_int(ea[2 * i]),
                           __float_as_int(ea[2 * i + 1]), 0);
}

// self-loop mean edge_attr per node
__global__ void k_la(const int* __restrict__ rowptr, const int4* __restrict__ edges,
                     float* __restrict__ la) {
    int n = (blockIdx.x * blockDim.x + threadIdx.x) >> 6;
    if (n >= NN) return;
    int lane = threadIdx.x & 63;
    int s0 = rowptr[n], e0 = rowptr[n + 1];
    float a0 = 0.f, a1 = 0.f;
    for (int e = s0 + lane; e < e0; e += 64) {
        int4 ep = edges[e];
        a0 += __int_as_float(ep.y);
        a1 += __int_as_float(ep.z);
    }
#pragma unroll
    for (int off = 32; off > 0; off >>= 1) {
        a0 += __shfl_xor(a0, off);
        a1 += __shfl_xor(a1, off);
    }
    if (lane == 0) {
        float d = fmaxf((float)(e0 - s0), 1.0f);
        la[2 * n] = a0 / d;
        la[2 * n + 1] = a1 / d;
    }
}

// ---------- Me[d,h] scaled by LOG2E ----------
template <int H, int C>
__global__ void k_me(const float* __restrict__ We, const float* __restrict__ aE,
                     float* __restrict__ me) {
    int t = threadIdx.x;
    if (t >= 2 * H) return;
    int d = t / H, hd = t % H;
    float s = 0.f;
    for (int c = 0; c < C; c++) s += We[d * H * C + hd * C + c] * aE[hd * C + c];
    me[t] = s * LOG2E;
}

// layer-1 prep: vS/vD (scaled by LOG2E)
__global__ void k_vsd(const float* __restrict__ W1, const float* __restrict__ aS1,
                      const float* __restrict__ aD1, float* __restrict__ vsd) {
    int t = threadIdx.x;
    if (t >= 40) return;
    const float* a = (t < 20) ? aS1 : aD1;
    int r = t % 20, hd = r / 5, i = r % 5;
    float s = 0.f;
    for (int c = 0; c < 32; c++) s += W1[i * 128 + hd * 32 + c] * a[hd * 32 + c];
    vsd[t] = s * LOG2E;
}

// layer-1 per-node: padded x + logits als1/ald1 (scaled)
__global__ void k_prep1(const float* __restrict__ x, const float* __restrict__ vsd,
                        float4* __restrict__ xp, float4* __restrict__ als1,
                        float4* __restrict__ ald1) {
    int n = blockIdx.x * blockDim.x + threadIdx.x;
    if (n >= NN) return;
    float x0 = x[5 * n], x1 = x[5 * n + 1], x2 = x[5 * n + 2], x3 = x[5 * n + 3],
          x4 = x[5 * n + 4];
    xp[2 * n] = make_float4(x0, x1, x2, x3);
    xp[2 * n + 1] = make_float4(x4, 0.f, 0.f, 0.f);
    float sv[4], dv[4];
#pragma unroll
    for (int hd = 0; hd < 4; hd++) {
        const float* vS = vsd + hd * 5;
        const float* vD = vsd + 20 + hd * 5;
        sv[hd] = x0 * vS[0] + x1 * vS[1] + x2 * vS[2] + x3 * vS[3] + x4 * vS[4];
        dv[hd] = x0 * vD[0] + x1 * vD[1] + x2 * vD[2] + x3 * vD[3] + x4 * vD[4];
    }
    als1[n] = make_float4(sv[0], sv[1], sv[2], sv[3]);
    ald1[n] = make_float4(dv[0], dv[1], dv[2], dv[3]);
}

// ---------- layer 1 agg: thread per (node, head); two-pass softmax; 5-dim x accum ----------
__global__ void k_agg1(const int* __restrict__ rowptr, const int4* __restrict__ edges,
                       const float4* __restrict__ xp, const float* __restrict__ als1,
                       const float* __restrict__ ald1, const float* __restrict__ la,
                       const float* __restrict__ me, float* __restrict__ xw) {
    int t = blockIdx.x * blockDim.x + threadIdx.x;
    if (t >= NN * 4) return;
    int n = t >> 2, hd = t & 3;
    float me0 = me[hd], me1 = me[4 + hd];
    float aldn = ald1[t];
    float aself = lrelu(als1[t] + aldn + la[2 * n] * me0 + la[2 * n + 1] * me1);
    int start = rowptr[n], end = rowptr[n + 1];
    // pass 1: segment max
    float m = aself;
    for (int e = start; e < end; ++e) {
        int4 ep = edges[e];
        float a = lrelu(als1[ep.x * 4 + hd] + aldn + __int_as_float(ep.y) * me0 +
                        __int_as_float(ep.z) * me1);
        m = fmaxf(m, a);
    }
    // pass 2: weighted x accumulation (pre-projection trick)
    float p0 = fexp2(aself - m);
    float den = p0;
    float4 xa = xp[2 * n];
    float xb = xp[2 * n + 1].x;
    float a0 = p0 * xa.x, a1 = p0 * xa.y, a2 = p0 * xa.z, a3 = p0 * xa.w, a4 = p0 * xb;
    for (int e = start; e < end; ++e) {
        int4 ep = edges[e];
        int s = ep.x;
        float a = lrelu(als1[s * 4 + hd] + aldn + __int_as_float(ep.y) * me0 +
                        __int_as_float(ep.z) * me1);
        float p = fexp2(a - m);
        den += p;
        float4 sa = xp[2 * s];
        float sb = xp[2 * s + 1].x;
        a0 += p * sa.x;
        a1 += p * sa.y;
        a2 += p * sa.z;
        a3 += p * sa.w;
        a4 += p * sb;
    }
    float r = 1.f / den;
    float* w = xw + (size_t)n * 20 + hd * 5;
    w[0] = a0 * r;
    w[1] = a1 * r;
    w[2] = a2 * r;
    w[3] = a3 * r;
    w[4] = a4 * r;
}

// ---------- layer 2 transform: act1 reconstructed in LDS, h2 = act1@W2, fused als/ald ----------
__global__ void k_l2trans(const float* __restrict__ xw, const float* __restrict__ W1,
                          const float* __restrict__ b1, const float* __restrict__ W2,
                          const float* __restrict__ aS2, const float* __restrict__ aD2,
                          float* __restrict__ h2, float* __restrict__ als2,
                          float* __restrict__ ald2) {
    __shared__ float sx[4 * 128];
    int nb = blockIdx.x * 4, t = threadIdx.x;
#pragma unroll
    for (int half = 0; half < 2; half++) {
        int item = t + half * 256;
        int l = item >> 7, ch = item & 127;
        int node = nb + l;
        float v = 0.f;
        if (node < NN) {
            int hd = ch >> 5;
            const float* w = xw + (size_t)node * 20 + hd * 5;
            v = w[0] * W1[ch] + w[1] * W1[128 + ch] + w[2] * W1[256 + ch] +
                w[3] * W1[384 + ch] + w[4] * W1[512 + ch] + b1[ch];
            v = elu1(v);
        }
        sx[item] = v;
    }
    __syncthreads();
    int l = t >> 6, j = t & 63;
    int node = nb + l;
    float acc = 0.f;
    for (int i = 0; i < 128; i++) acc += sx[l * 128 + i] * W2[i * 64 + j];
    float pS = acc * aS2[j], pD = acc * aD2[j];
#pragma unroll
    for (int off = 16; off > 0; off >>= 1) {
        pS += __shfl_xor(pS, off);
        pD += __shfl_xor(pD, off);
    }
    if (node < NN) {
        h2[(size_t)node * 64 + j] = acc;
        if ((j & 31) == 0) {
            int hd = j >> 5;
            als2[node * 2 + hd] = pS * LOG2E;
            ald2[node * 2 + hd] = pD * LOG2E;
        }
    }
}

// ---------- layer 2 agg: thread per (node, head-half); two-pass; fused ELU + W3 proj -> h3 ----------
__global__ void k_agg2(const int* __restrict__ rowptr, const int4* __restrict__ edges,
                       const float* __restrict__ h2, const float* __restrict__ als2,
                       const float* __restrict__ ald2, const float* __restrict__ la,
                       const float* __restrict__ me, const float* __restrict__ b2,
                       const float* __restrict__ W3, float* __restrict__ h3) {
    int t = blockIdx.x * blockDim.x + threadIdx.x;
    if (t >= NN * 4) return;
    int n = t >> 2, sub = t & 3, hd = sub >> 1, qh = sub & 1;
    int cbase = hd * 32 + qh * 16;
    float me0 = me[hd], me1 = me[2 + hd];
    float aldn = ald2[n * 2 + hd];
    float aself = lrelu(als2[n * 2 + hd] + aldn + la[2 * n] * me0 + la[2 * n + 1] * me1);
    int start = rowptr[n], end = rowptr[n + 1];
    // pass 1: segment max
    float m = aself;
    for (int e = start; e < end; ++e) {
        int4 ep = edges[e];
        float a = lrelu(als2[ep.x * 2 + hd] + aldn + __int_as_float(ep.y) * me0 +
                        __int_as_float(ep.z) * me1);
        m = fmaxf(m, a);
    }
    // pass 2: 16-channel weighted aggregation
    float p0 = fexp2(aself - m);
    float den = p0;
    float acc[16];
    const float4* hn = (const float4*)(h2 + (size_t)n * 64 + cbase);
#pragma unroll
    for (int q = 0; q < 4; q++) {
        float4 v = hn[q];
        acc[4 * q] = p0 * v.x;
        acc[4 * q + 1] = p0 * v.y;
        acc[4 * q + 2] = p0 * v.z;
        acc[4 * q + 3] = p0 * v.w;
    }
    for (int e = start; e < end; ++e) {
        int4 ep = edges[e];
        int s = ep.x;
        float a = lrelu(als2[s * 2 + hd] + aldn + __int_as_float(ep.y) * me0 +
                        __int_as_float(ep.z) * me1);
        float p = fexp2(a - m);
        den += p;
        const float4* hs = (const float4*)(h2 + (size_t)s * 64 + cbase);
#pragma unroll
        for (int q = 0; q < 4; q++) {
            float4 v = hs[q];
            acc[4 * q] += p * v.x;
            acc[4 * q + 1] += p * v.y;
            acc[4 * q + 2] += p * v.z;
            acc[4 * q + 3] += p * v.w;
        }
    }
    // epilogue: act2 = elu(acc/den + b2); partial h3 = act2 . W3
    float r = 1.f / den;
    float part = 0.f;
#pragma unroll
    for (int c = 0; c < 16; c++) {
        float v = elu1(acc[c] * r + b2[cbase + c]);
        part += v * W3[cbase + c];
    }
    part += __shfl_xor(part, 1);
    part += __shfl_xor(part, 2);
    if (sub == 0) h3[n] = part;
}

// ---------- layer 3 agg: H=1,C=1; wave per node, lanes parallel over edges ----------
__global__ void k_agg3(const int* __restrict__ rowptr, const int4* __restrict__ edges,
                       const float* __restrict__ h, const float* __restrict__ aS3,
                       const float* __restrict__ aD3, const float* __restrict__ la,
                       const float* __restrict__ me, const float* __restrict__ b,
                       float* __restrict__ out) {
    int n = (blockIdx.x * blockDim.x + threadIdx.x) >> 6;
    if (n >= NN) return;
    int lane = threadIdx.x & 63;
    float me0 = me[0], me1 = me[1];
    float aSs = aS3[0] * LOG2E, aDs = aD3[0] * LOG2E;
    float hn = h[n];
    float ald_n = hn * aDs;
    int start = rowptr[n], end = rowptr[n + 1];
    float m = -1e30f, den = 0.f, num = 0.f;
    for (int e = start + lane; e < end; e += 64) {
        int4 ep = edges[e];
        int s = ep.x;
        float hv = h[s];
        float a = lrelu(hv * aSs + ald_n + __int_as_float(ep.y) * me0 +
                        __int_as_float(ep.z) * me1);
        float mn = fmaxf(m, a);
        float ex = fexp2(-fabsf(a - m));
        bool gt = a > m;
        float sc = gt ? ex : 1.f;
        float p = gt ? 1.f : ex;
        den = den * sc + p;
        num = num * sc + p * hv;
        m = mn;
    }
#pragma unroll
    for (int off = 1; off < 64; off <<= 1) {
        float mo = __shfl_xor(m, off);
        float dn = __shfl_xor(den, off);
        float nm = __shfl_xor(num, off);
        float ex = fexp2(-fabsf(m - mo));
        bool gt = mo > m;
        float s1 = gt ? ex : 1.f;
        float s2 = gt ? 1.f : ex;
        den = den * s1 + dn * s2;
        num = num * s1 + nm * s2;
        m = fmaxf(m, mo);
    }
    if (lane == 0) {
        float aself = lrelu(hn * aSs + ald_n + la[2 * n] * me0 + la[2 * n + 1] * me1);
        float ex = fexp2(-fabsf(aself - m));
        bool gt = aself > m;
        float sc = gt ? ex : 1.f;
        float p = gt ? 1.f : ex;
        den = den * sc + p;
        num = num * sc + p * hn;
        float v = num / den + b[0];
        out[n] = 1.f / (1.f + __expf(-v));
    }
}

extern "C" void kernel_launch(void* const* d_in, const int* in_sizes, int n_in,
                              void* d_out, int out_size, void* d_ws, size_t ws_size,
                              hipStream_t stream) {
    const float* x   = (const float*)d_in[0];
    const int*   ei  = (const int*)d_in[1];
    const float* ea  = (const float*)d_in[2];
    const float* W1  = (const float*)d_in[3];
    const float* aS1 = (const float*)d_in[4];
    const float* aD1 = (const float*)d_in[5];
    const float* We1 = (const float*)d_in[6];
    const float* aE1 = (const float*)d_in[7];
    const float* b1  = (const float*)d_in[8];
    const float* W2  = (const float*)d_in[9];
    const float* aS2 = (const float*)d_in[10];
    const float* aD2 = (const float*)d_in[11];
    const float* We2 = (const float*)d_in[12];
    const float* aE2 = (const float*)d_in[13];
    const float* b2  = (const float*)d_in[14];
    const float* W3  = (const float*)d_in[15];
    const float* aS3 = (const float*)d_in[16];
    const float* aD3 = (const float*)d_in[17];
    const float* We3 = (const float*)d_in[18];
    const float* aE3 = (const float*)d_in[19];
    const float* b3  = (const float*)d_in[20];

    const int* srcv = ei;
    const int* dstv = ei + NE;

    char* basep = (char*)d_ws;
    size_t off = 0;
    auto alloc = [&](size_t nbytes) -> void* {
        void* p = basep + off;
        off += (nbytes + 255) & ~(size_t)255;
        return p;
    };
    int*    cnt    = (int*)alloc((size_t)NN * 4);
    float*  la     = (float*)alloc((size_t)NN * 8);
    int*    rp1    = (int*)alloc((size_t)NN * 4);
    int*    rowptr = (int*)alloc((size_t)(NN + 1) * 4);
    int*    wptr   = (int*)alloc((size_t)NN * 4);
    int*    bsum   = (int*)alloc(512);
    int*    boff   = (int*)alloc(512);
    int4*   edges  = (int4*)alloc((size_t)NE * 16);
    float*  me     = (float*)alloc(256);
    float*  vsd    = (float*)alloc(256);
    float4* xp     = (float4*)alloc((size_t)NN * 32);
    float4* als1   = (float4*)alloc((size_t)NN * 16);
    float4* ald1   = (float4*)alloc((size_t)NN * 16);
    float*  xw     = (float*)alloc((size_t)NN * 80);
    float*  h2     = (float*)alloc((size_t)NN * 256);
    float*  als2   = (float*)alloc((size_t)NN * 8);
    float*  ald2   = (float*)alloc((size_t)NN * 8);
    float*  h3     = (float*)alloc((size_t)NN * 4);
    (void)ws_size; (void)in_sizes; (void)n_in; (void)out_size;

    auto cdiv = [](long long a, long long b) { return (int)((a + b - 1) / b); };
    const int BS = 256;

    // ---- CSR build ----
    hipMemsetAsync(cnt, 0, (size_t)NN * 4, stream);
    k_count<<<cdiv(NE, BS), BS, 0, stream>>>(dstv, cnt);
    k_scanA<<<SCAN_NB, 256, 0, stream>>>(cnt, rp1, bsum);
    k_scanB<<<1, 128, 0, stream>>>(bsum, boff);
    k_scanC<<<cdiv(NN, BS), BS, 0, stream>>>(rp1, boff, cnt, rowptr, wptr);
    k_scatter<<<cdiv(NE, BS), BS, 0, stream>>>(srcv, dstv, ea, wptr, edges);
    k_la<<<cdiv(NN, 4), 256, 0, stream>>>(rowptr, edges, la);

    // ================= Layer 1: IN=5, H=4, C=32 (ELU) =================
    k_me<4, 32><<<1, 64, 0, stream>>>(We1, aE1, me);
    k_vsd<<<1, 64, 0, stream>>>(W1, aS1, aD1, vsd);
    k_prep1<<<cdiv(NN, BS), BS, 0, stream>>>(x, vsd, xp, als1, ald1);
    k_agg1<<<cdiv((long long)NN * 4, BS), BS, 0, stream>>>(rowptr, edges, xp,
                                                           (const float*)als1,
                                                           (const float*)ald1, la, me, xw);

    // ================= Layer 2: IN=128, H=2, C=32 (ELU) =================
    k_l2trans<<<cdiv(NN, 4), 256, 0, stream>>>(xw, W1, b1, W2, aS2, aD2, h2, als2, ald2);
    k_me<2, 32><<<1, 64, 0, stream>>>(We2, aE2, me);
    k_agg2<<<cdiv((long long)NN * 4, BS), BS, 0, stream>>>(rowptr, edges, h2, als2, ald2,
                                                           la, me, b2, W3, h3);

    // ================= Layer 3: IN=64, H=1, C=1 (sigmoid) =================
    k_me<1, 1><<<1, 64, 0, stream>>>(We3, aE3, me);
    k_agg3<<<cdiv(NN, 4), 256, 0, stream>>>(rowptr, edges, h3, aS3, aD3, la, me,
                                            b3, (float*)d_out);
}

// Round 6
// 544.337 us; speedup vs baseline: 32.4110x; 1.1220x over previous
//
#include <hip/hip_runtime.h>
#include <math.h>

#define NN 100000
#define NE 1600000
#define SCAN_CHUNK 1024
#define SCAN_NB ((NN + SCAN_CHUNK - 1) / SCAN_CHUNK)  // 98
#define LOG2E 1.44269504088896f

__device__ __forceinline__ float lrelu(float x) { return fmaxf(x, 0.2f * x); }
__device__ __forceinline__ float elu1(float x) { return x > 0.f ? x : (__expf(x) - 1.f); }
__device__ __forceinline__ float fexp2(float x) {
#if __has_builtin(__builtin_amdgcn_exp2f)
    return __builtin_amdgcn_exp2f(x);
#else
    return exp2f(x);
#endif
}

// ---------- CSR build ----------
__global__ void k_count(const int* __restrict__ dst, int* __restrict__ cnt) {
    int i = blockIdx.x * blockDim.x + threadIdx.x;
    if (i >= NE) return;
    atomicAdd(cnt + dst[i], 1);
}

__global__ void k_scanA(const int* __restrict__ cnt, int* __restrict__ rp1,
                        int* __restrict__ bsum) {
    __shared__ int s[256];
    int b = blockIdx.x, t = threadIdx.x;
    int base = b * SCAN_CHUNK + t * 4;
    int v[4], sum = 0;
#pragma unroll
    for (int i = 0; i < 4; i++) {
        v[i] = (base + i < NN) ? cnt[base + i] : 0;
        sum += v[i];
    }
    s[t] = sum;
    __syncthreads();
    for (int off = 1; off < 256; off <<= 1) {
        int x = (t >= off) ? s[t - off] : 0;
        __syncthreads();
        if (t >= off) s[t] += x;
        __syncthreads();
    }
    int run = s[t] - sum;
#pragma unroll
    for (int i = 0; i < 4; i++) {
        run += v[i];
        if (base + i < NN) rp1[base + i] = run;
    }
    if (t == 255) bsum[b] = s[255];
}

__global__ void k_scanB(const int* __restrict__ bsum, int* __restrict__ boff) {
    __shared__ int s[128];
    int t = threadIdx.x;
    int v = (t < SCAN_NB) ? bsum[t] : 0;
    s[t] = v;
    __syncthreads();
    for (int off = 1; off < 128; off <<= 1) {
        int x = (t >= off) ? s[t - off] : 0;
        __syncthreads();
        if (t >= off) s[t] += x;
        __syncthreads();
    }
    if (t < SCAN_NB) boff[t] = s[t] - v;
}

__global__ void k_scanC(const int* __restrict__ rp1, const int* __restrict__ boff,
                        const int* __restrict__ cnt, int* __restrict__ rowptr,
                        int* __restrict__ wptr) {
    int i = blockIdx.x * blockDim.x + threadIdx.x;
    if (i >= NN) return;
    int inc = rp1[i] + boff[i / SCAN_CHUNK];
    rowptr[i + 1] = inc;
    wptr[i] = inc - cnt[i];
    if (i == 0) rowptr[0] = 0;
}

__global__ void k_scatter(const int* __restrict__ src, const int* __restrict__ dst,
                          const float* __restrict__ ea, int* __restrict__ wptr,
                          int4* __restrict__ edges) {
    int i = blockIdx.x * blockDim.x + threadIdx.x;
    if (i >= NE) return;
    int d = dst[i];
    int pos = atomicAdd(wptr + d, 1);
    edges[pos] = make_int4(src[i], __float_as_int(ea[2 * i]),
                           __float_as_int(ea[2 * i + 1]), 0);
}

// self-loop mean edge_attr per node
__global__ void k_la(const int* __restrict__ rowptr, const int4* __restrict__ edges,
                     float* __restrict__ la) {
    int n = (blockIdx.x * blockDim.x + threadIdx.x) >> 6;
    if (n >= NN) return;
    int lane = threadIdx.x & 63;
    int s0 = rowptr[n], e0 = rowptr[n + 1];
    float a0 = 0.f, a1 = 0.f;
    for (int e = s0 + lane; e < e0; e += 64) {
        int4 ep = edges[e];
        a0 += __int_as_float(ep.y);
        a1 += __int_as_float(ep.z);
    }
#pragma unroll
    for (int off = 32; off > 0; off >>= 1) {
        a0 += __shfl_xor(a0, off);
        a1 += __shfl_xor(a1, off);
    }
    if (lane == 0) {
        float d = fmaxf((float)(e0 - s0), 1.0f);
        la[2 * n] = a0 / d;
        la[2 * n + 1] = a1 / d;
    }
}

// ---------- Me[d,h] scaled by LOG2E ----------
template <int H, int C>
__global__ void k_me(const float* __restrict__ We, const float* __restrict__ aE,
                     float* __restrict__ me) {
    int t = threadIdx.x;
    if (t >= 2 * H) return;
    int d = t / H, hd = t % H;
    float s = 0.f;
    for (int c = 0; c < C; c++) s += We[d * H * C + hd * C + c] * aE[hd * C + c];
    me[t] = s * LOG2E;
}

// layer-1 prep: vS/vD (scaled by LOG2E)
__global__ void k_vsd(const float* __restrict__ W1, const float* __restrict__ aS1,
                      const float* __restrict__ aD1, float* __restrict__ vsd) {
    int t = threadIdx.x;
    if (t >= 40) return;
    const float* a = (t < 20) ? aS1 : aD1;
    int r = t % 20, hd = r / 5, i = r % 5;
    float s = 0.f;
    for (int c = 0; c < 32; c++) s += W1[i * 128 + hd * 32 + c] * a[hd * 32 + c];
    vsd[t] = s * LOG2E;
}

// layer-1 per-node: padded x + logits als1/ald1 (scaled)
__global__ void k_prep1(const float* __restrict__ x, const float* __restrict__ vsd,
                        float4* __restrict__ xp, float4* __restrict__ als1,
                        float4* __restrict__ ald1) {
    int n = blockIdx.x * blockDim.x + threadIdx.x;
    if (n >= NN) return;
    float x0 = x[5 * n], x1 = x[5 * n + 1], x2 = x[5 * n + 2], x3 = x[5 * n + 3],
          x4 = x[5 * n + 4];
    xp[2 * n] = make_float4(x0, x1, x2, x3);
    xp[2 * n + 1] = make_float4(x4, 0.f, 0.f, 0.f);
    float sv[4], dv[4];
#pragma unroll
    for (int hd = 0; hd < 4; hd++) {
        const float* vS = vsd + hd * 5;
        const float* vD = vsd + 20 + hd * 5;
        sv[hd] = x0 * vS[0] + x1 * vS[1] + x2 * vS[2] + x3 * vS[3] + x4 * vS[4];
        dv[hd] = x0 * vD[0] + x1 * vD[1] + x2 * vD[2] + x3 * vD[3] + x4 * vD[4];
    }
    als1[n] = make_float4(sv[0], sv[1], sv[2], sv[3]);
    ald1[n] = make_float4(dv[0], dv[1], dv[2], dv[3]);
}

// ---------- layer 1 agg: thread per (node, head); two-pass softmax; 5-dim x accum ----------
__global__ void k_agg1(const int* __restrict__ rowptr, const int4* __restrict__ edges,
                       const float4* __restrict__ xp, const float* __restrict__ als1,
                       const float* __restrict__ ald1, const float* __restrict__ la,
                       const float* __restrict__ me, float* __restrict__ xw) {
    int t = blockIdx.x * blockDim.x + threadIdx.x;
    if (t >= NN * 4) return;
    int n = t >> 2, hd = t & 3;
    float me0 = me[hd], me1 = me[4 + hd];
    float aldn = ald1[t];
    float aself = lrelu(als1[t] + aldn + la[2 * n] * me0 + la[2 * n + 1] * me1);
    int start = rowptr[n], end = rowptr[n + 1];
    // pass 1: segment max
    float m = aself;
    for (int e = start; e < end; ++e) {
        int4 ep = edges[e];
        float a = lrelu(als1[ep.x * 4 + hd] + aldn + __int_as_float(ep.y) * me0 +
                        __int_as_float(ep.z) * me1);
        m = fmaxf(m, a);
    }
    // pass 2: weighted x accumulation (pre-projection trick)
    float p0 = fexp2(aself - m);
    float den = p0;
    float4 xa = xp[2 * n];
    float xb = xp[2 * n + 1].x;
    float a0 = p0 * xa.x, a1 = p0 * xa.y, a2 = p0 * xa.z, a3 = p0 * xa.w, a4 = p0 * xb;
    for (int e = start; e < end; ++e) {
        int4 ep = edges[e];
        int s = ep.x;
        float a = lrelu(als1[s * 4 + hd] + aldn + __int_as_float(ep.y) * me0 +
                        __int_as_float(ep.z) * me1);
        float p = fexp2(a - m);
        den += p;
        float4 sa = xp[2 * s];
        float sb = xp[2 * s + 1].x;
        a0 += p * sa.x;
        a1 += p * sa.y;
        a2 += p * sa.z;
        a3 += p * sa.w;
        a4 += p * sb;
    }
    float r = 1.f / den;
    float* w = xw + (size_t)n * 20 + hd * 5;
    w[0] = a0 * r;
    w[1] = a1 * r;
    w[2] = a2 * r;
    w[3] = a3 * r;
    w[4] = a4 * r;
}

// ---------- layer 2 transform: register-blocked tile GEMM ----------
// 64 nodes/block; act1 reconstructed into LDS (pad 132); thread = 4 nodes x 4 ch.
__global__ void __launch_bounds__(256) k_l2trans(
        const float* __restrict__ xw, const float* __restrict__ W1,
        const float* __restrict__ b1, const float* __restrict__ W2,
        const float* __restrict__ aS2, const float* __restrict__ aD2,
        float* __restrict__ h2, float* __restrict__ als2, float* __restrict__ ald2) {
    __shared__ float sx[64 * 132];
    int nb = blockIdx.x * 64, t = threadIdx.x;
    // phase 1: reconstruct act1 = elu(xw-combined @ W1 + b1) into LDS
    {
        int nl = t >> 2, q = t & 3;
        int node = nb + nl;
        float w[20];
        if (node < NN) {
#pragma unroll
            for (int i = 0; i < 20; i++) w[i] = xw[(size_t)node * 20 + i];
        } else {
#pragma unroll
            for (int i = 0; i < 20; i++) w[i] = 0.f;
        }
#pragma unroll
        for (int k = 0; k < 32; k++) {
            int ch = q + 4 * k;
            int hd = ch >> 5;
            float v = w[hd * 5] * W1[ch] + w[hd * 5 + 1] * W1[128 + ch] +
                      w[hd * 5 + 2] * W1[256 + ch] + w[hd * 5 + 3] * W1[384 + ch] +
                      w[hd * 5 + 4] * W1[512 + ch] + b1[ch];
            sx[nl * 132 + ch] = (node < NN) ? elu1(v) : 0.f;
        }
    }
    __syncthreads();
    // phase 2: h2 = act1 @ W2 (M=64, K=128, N=64), 4 nodes x 4 j per thread
    int jq = t & 15, ng = t >> 4;
    int j4 = jq * 4;
    float4 acc[4];
#pragma unroll
    for (int p = 0; p < 4; p++) acc[p] = make_float4(0.f, 0.f, 0.f, 0.f);
    for (int ic = 0; ic < 128; ic += 4) {
        float4 s[4];
#pragma unroll
        for (int p = 0; p < 4; p++)
            s[p] = *(const float4*)(sx + (ng * 4 + p) * 132 + ic);
#pragma unroll
        for (int r = 0; r < 4; r++) {
            float4 wv = *(const float4*)(W2 + (ic + r) * 64 + j4);
#pragma unroll
            for (int p = 0; p < 4; p++) {
                float sv = (r == 0) ? s[p].x : (r == 1) ? s[p].y : (r == 2) ? s[p].z : s[p].w;
                acc[p].x += sv * wv.x;
                acc[p].y += sv * wv.y;
                acc[p].z += sv * wv.z;
                acc[p].w += sv * wv.w;
            }
        }
    }
    // epilogue: attention logit partials + reduce over the 8 jq lanes of this head
    int hd = jq >> 3;
    float4 a_s = *(const float4*)(aS2 + j4);
    float4 a_d = *(const float4*)(aD2 + j4);
    float pS[4], pD[4];
#pragma unroll
    for (int p = 0; p < 4; p++) {
        pS[p] = acc[p].x * a_s.x + acc[p].y * a_s.y + acc[p].z * a_s.z + acc[p].w * a_s.w;
        pD[p] = acc[p].x * a_d.x + acc[p].y * a_d.y + acc[p].z * a_d.z + acc[p].w * a_d.w;
    }
#pragma unroll
    for (int off = 1; off < 8; off <<= 1) {
#pragma unroll
        for (int p = 0; p < 4; p++) {
            pS[p] += __shfl_xor(pS[p], off);
            pD[p] += __shfl_xor(pD[p], off);
        }
    }
#pragma unroll
    for (int p = 0; p < 4; p++) {
        int node = nb + ng * 4 + p;
        if (node < NN) {
            *(float4*)(h2 + (size_t)node * 64 + j4) = acc[p];
            if ((jq & 7) == 0) {
                als2[node * 2 + hd] = pS[p] * LOG2E;
                ald2[node * 2 + hd] = pD[p] * LOG2E;
            }
        }
    }
}

// ---------- layer 2 agg: thread per (node, head-half); two-pass; fused ELU + W3 proj -> h3 ----------
__global__ void k_agg2(const int* __restrict__ rowptr, const int4* __restrict__ edges,
                       const float* __restrict__ h2, const float* __restrict__ als2,
                       const float* __restrict__ ald2, const float* __restrict__ la,
                       const float* __restrict__ me, const float* __restrict__ b2,
                       const float* __restrict__ W3, float* __restrict__ h3) {
    int t = blockIdx.x * blockDim.x + threadIdx.x;
    if (t >= NN * 4) return;
    int n = t >> 2, sub = t & 3, hd = sub >> 1, qh = sub & 1;
    int cbase = hd * 32 + qh * 16;
    float me0 = me[hd], me1 = me[2 + hd];
    float aldn = ald2[n * 2 + hd];
    float aself = lrelu(als2[n * 2 + hd] + aldn + la[2 * n] * me0 + la[2 * n + 1] * me1);
    int start = rowptr[n], end = rowptr[n + 1];
    // pass 1: segment max
    float m = aself;
    for (int e = start; e < end; ++e) {
        int4 ep = edges[e];
        float a = lrelu(als2[ep.x * 2 + hd] + aldn + __int_as_float(ep.y) * me0 +
                        __int_as_float(ep.z) * me1);
        m = fmaxf(m, a);
    }
    // pass 2: 16-channel weighted aggregation
    float p0 = fexp2(aself - m);
    float den = p0;
    float acc[16];
    const float4* hn = (const float4*)(h2 + (size_t)n * 64 + cbase);
#pragma unroll
    for (int q = 0; q < 4; q++) {
        float4 v = hn[q];
        acc[4 * q] = p0 * v.x;
        acc[4 * q + 1] = p0 * v.y;
        acc[4 * q + 2] = p0 * v.z;
        acc[4 * q + 3] = p0 * v.w;
    }
    for (int e = start; e < end; ++e) {
        int4 ep = edges[e];
        int s = ep.x;
        float a = lrelu(als2[s * 2 + hd] + aldn + __int_as_float(ep.y) * me0 +
                        __int_as_float(ep.z) * me1);
        float p = fexp2(a - m);
        den += p;
        const float4* hs = (const float4*)(h2 + (size_t)s * 64 + cbase);
#pragma unroll
        for (int q = 0; q < 4; q++) {
            float4 v = hs[q];
            acc[4 * q] += p * v.x;
            acc[4 * q + 1] += p * v.y;
            acc[4 * q + 2] += p * v.z;
            acc[4 * q + 3] += p * v.w;
        }
    }
    // epilogue: act2 = elu(acc/den + b2); partial h3 = act2 . W3
    float r = 1.f / den;
    float part = 0.f;
#pragma unroll
    for (int c = 0; c < 16; c++) {
        float v = elu1(acc[c] * r + b2[cbase + c]);
        part += v * W3[cbase + c];
    }
    part += __shfl_xor(part, 1);
    part += __shfl_xor(part, 2);
    if (sub == 0) h3[n] = part;
}

// ---------- layer 3 agg: H=1,C=1; wave per node, lanes parallel over edges ----------
__global__ void k_agg3(const int* __restrict__ rowptr, const int4* __restrict__ edges,
                       const float* __restrict__ h, const float* __restrict__ aS3,
                       const float* __restrict__ aD3, const float* __restrict__ la,
                       const float* __restrict__ me, const float* __restrict__ b,
                       float* __restrict__ out) {
    int n = (blockIdx.x * blockDim.x + threadIdx.x) >> 6;
    if (n >= NN) return;
    int lane = threadIdx.x & 63;
    float me0 = me[0], me1 = me[1];
    float aSs = aS3[0] * LOG2E, aDs = aD3[0] * LOG2E;
    float hn = h[n];
    float ald_n = hn * aDs;
    int start = rowptr[n], end = rowptr[n + 1];
    float m = -1e30f, den = 0.f, num = 0.f;
    for (int e = start + lane; e < end; e += 64) {
        int4 ep = edges[e];
        int s = ep.x;
        float hv = h[s];
        float a = lrelu(hv * aSs + ald_n + __int_as_float(ep.y) * me0 +
                        __int_as_float(ep.z) * me1);
        float mn = fmaxf(m, a);
        float ex = fexp2(-fabsf(a - m));
        bool gt = a > m;
        float sc = gt ? ex : 1.f;
        float p = gt ? 1.f : ex;
        den = den * sc + p;
        num = num * sc + p * hv;
        m = mn;
    }
#pragma unroll
    for (int off = 1; off < 64; off <<= 1) {
        float mo = __shfl_xor(m, off);
        float dn = __shfl_xor(den, off);
        float nm = __shfl_xor(num, off);
        float ex = fexp2(-fabsf(m - mo));
        bool gt = mo > m;
        float s1 = gt ? ex : 1.f;
        float s2 = gt ? 1.f : ex;
        den = den * s1 + dn * s2;
        num = num * s1 + nm * s2;
        m = fmaxf(m, mo);
    }
    if (lane == 0) {
        float aself = lrelu(hn * aSs + ald_n + la[2 * n] * me0 + la[2 * n + 1] * me1);
        float ex = fexp2(-fabsf(aself - m));
        bool gt = aself > m;
        float sc = gt ? ex : 1.f;
        float p = gt ? 1.f : ex;
        den = den * sc + p;
        num = num * sc + p * hn;
        float v = num / den + b[0];
        out[n] = 1.f / (1.f + __expf(-v));
    }
}

extern "C" void kernel_launch(void* const* d_in, const int* in_sizes, int n_in,
                              void* d_out, int out_size, void* d_ws, size_t ws_size,
                              hipStream_t stream) {
    const float* x   = (const float*)d_in[0];
    const int*   ei  = (const int*)d_in[1];
    const float* ea  = (const float*)d_in[2];
    const float* W1  = (const float*)d_in[3];
    const float* aS1 = (const float*)d_in[4];
    const float* aD1 = (const float*)d_in[5];
    const float* We1 = (const float*)d_in[6];
    const float* aE1 = (const float*)d_in[7];
    const float* b1  = (const float*)d_in[8];
    const float* W2  = (const float*)d_in[9];
    const float* aS2 = (const float*)d_in[10];
    const float* aD2 = (const float*)d_in[11];
    const float* We2 = (const float*)d_in[12];
    const float* aE2 = (const float*)d_in[13];
    const float* b2  = (const float*)d_in[14];
    const float* W3  = (const float*)d_in[15];
    const float* aS3 = (const float*)d_in[16];
    const float* aD3 = (const float*)d_in[17];
    const float* We3 = (const float*)d_in[18];
    const float* aE3 = (const float*)d_in[19];
    const float* b3  = (const float*)d_in[20];

    const int* srcv = ei;
    const int* dstv = ei + NE;

    char* basep = (char*)d_ws;
    size_t off = 0;
    auto alloc = [&](size_t nbytes) -> void* {
        void* p = basep + off;
        off += (nbytes + 255) & ~(size_t)255;
        return p;
    };
    int*    cnt    = (int*)alloc((size_t)NN * 4);
    float*  la     = (float*)alloc((size_t)NN * 8);
    int*    rp1    = (int*)alloc((size_t)NN * 4);
    int*    rowptr = (int*)alloc((size_t)(NN + 1) * 4);
    int*    wptr   = (int*)alloc((size_t)NN * 4);
    int*    bsum   = (int*)alloc(512);
    int*    boff   = (int*)alloc(512);
    int4*   edges  = (int4*)alloc((size_t)NE * 16);
    float*  me     = (float*)alloc(256);
    float*  vsd    = (float*)alloc(256);
    float4* xp     = (float4*)alloc((size_t)NN * 32);
    float4* als1   = (float4*)alloc((size_t)NN * 16);
    float4* ald1   = (float4*)alloc((size_t)NN * 16);
    float*  xw     = (float*)alloc((size_t)NN * 80);
    float*  h2     = (float*)alloc((size_t)NN * 256);
    float*  als2   = (float*)alloc((size_t)NN * 8);
    float*  ald2   = (float*)alloc((size_t)NN * 8);
    float*  h3     = (float*)alloc((size_t)NN * 4);
    (void)ws_size; (void)in_sizes; (void)n_in; (void)out_size;

    auto cdiv = [](long long a, long long b) { return (int)((a + b - 1) / b); };
    const int BS = 256;

    // ---- CSR build ----
    hipMemsetAsync(cnt, 0, (size_t)NN * 4, stream);
    k_count<<<cdiv(NE, BS), BS, 0, stream>>>(dstv, cnt);
    k_scanA<<<SCAN_NB, 256, 0, stream>>>(cnt, rp1, bsum);
    k_scanB<<<1, 128, 0, stream>>>(bsum, boff);
    k_scanC<<<cdiv(NN, BS), BS, 0, stream>>>(rp1, boff, cnt, rowptr, wptr);
    k_scatter<<<cdiv(NE, BS), BS, 0, stream>>>(srcv, dstv, ea, wptr, edges);
    k_la<<<cdiv(NN, 4), 256, 0, stream>>>(rowptr, edges, la);

    // ================= Layer 1: IN=5, H=4, C=32 (ELU) =================
    k_me<4, 32><<<1, 64, 0, stream>>>(We1, aE1, me);
    k_vsd<<<1, 64, 0, stream>>>(W1, aS1, aD1, vsd);
    k_prep1<<<cdiv(NN, BS), BS, 0, stream>>>(x, vsd, xp, als1, ald1);
    k_agg1<<<cdiv((long long)NN * 4, BS), BS, 0, stream>>>(rowptr, edges, xp,
                                                           (const float*)als1,
                                                           (const float*)ald1, la, me, xw);

    // ================= Layer 2: IN=128, H=2, C=32 (ELU) =================
    k_l2trans<<<cdiv(NN, 64), 256, 0, stream>>>(xw, W1, b1, W2, aS2, aD2, h2, als2, ald2);
    k_me<2, 32><<<1, 64, 0, stream>>>(We2, aE2, me);
    k_agg2<<<cdiv((long long)NN * 4, BS), BS, 0, stream>>>(rowptr, edges, h2, als2, ald2,
                                                           la, me, b2, W3, h3);

    // ================= Layer 3: IN=64, H=1, C=1 (sigmoid) =================
    k_me<1, 1><<<1, 64, 0, stream>>>(We3, aE3, me);
    k_agg3<<<cdiv(NN, 4), 256, 0, stream>>>(rowptr, edges, h3, aS3, aD3, la, me,
                                            b3, (float*)d_out);
}

// Round 7
// 434.894 us; speedup vs baseline: 40.5674x; 1.2517x over previous
//
#include <hip/hip_runtime.h>
#include <math.h>

#define NN 100000
#define NE 1600000
#define NPB 256                     // nodes per bucket (dst >> 8)
#define NB 391                      // ceil(NN / NPB)
#define NCHUNK 256                  // binning chunks
#define CH ((NE + NCHUNK - 1) / NCHUNK)  // 6250 edges per chunk
#define LOG2E 1.44269504088896f

__device__ __forceinline__ float lrelu(float x) { return fmaxf(x, 0.2f * x); }
__device__ __forceinline__ float elu1(float x) { return x > 0.f ? x : (__expf(x) - 1.f); }
__device__ __forceinline__ float fexp2(float x) {
#if __has_builtin(__builtin_amdgcn_exp2f)
    return __builtin_amdgcn_exp2f(x);
#else
    return exp2f(x);
#endif
}

// ================= binned CSR build =================
// A0: per-chunk bucket histogram -> global bucket counts
__global__ void __launch_bounds__(256) k_binA0(const int* __restrict__ dst,
                                               int* __restrict__ bucket_cnt) {
    __shared__ int hist[NB];
    int t = threadIdx.x;
    for (int b = t; b < NB; b += 256) hist[b] = 0;
    __syncthreads();
    int c0 = blockIdx.x * CH, c1 = min(NE, c0 + CH);
    for (int e = c0 + t; e < c1; e += 256) atomicAdd(&hist[dst[e] >> 8], 1);
    __syncthreads();
    for (int b = t; b < NB; b += 256)
        if (hist[b]) atomicAdd(&bucket_cnt[b], hist[b]);
}

// scan bucket counts -> bucket_base[NB+1], bucket_tail
__global__ void k_bscan(const int* __restrict__ bucket_cnt, int* __restrict__ bucket_base,
                        int* __restrict__ bucket_tail) {
    __shared__ int s[512];
    int t = threadIdx.x;
    int v = (t < NB) ? bucket_cnt[t] : 0;
    s[t] = v;
    __syncthreads();
    for (int off = 1; off < 512; off <<= 1) {
        int x = (t >= off) ? s[t - off] : 0;
        __syncthreads();
        if (t >= off) s[t] += x;
        __syncthreads();
    }
    if (t < NB) {
        int ex = s[t] - v;
        bucket_base[t] = ex;
        bucket_tail[t] = ex;
        if (t == NB - 1) bucket_base[NB] = s[t];
    }
}

// A2: re-read chunk, reserve per-bucket space, write bucket-grouped records
// record = {src, ea0, ea1, dst}
__global__ void __launch_bounds__(256) k_binA2(const int* __restrict__ src,
                                               const int* __restrict__ dst,
                                               const float* __restrict__ ea,
                                               int* __restrict__ bucket_tail,
                                               int4* __restrict__ binned) {
    __shared__ int hist[NB], base_l[NB], cursor[NB];
    int t = threadIdx.x;
    for (int b = t; b < NB; b += 256) {
        hist[b] = 0;
        cursor[b] = 0;
    }
    __syncthreads();
    int c0 = blockIdx.x * CH, c1 = min(NE, c0 + CH);
    for (int e = c0 + t; e < c1; e += 256) atomicAdd(&hist[dst[e] >> 8], 1);
    __syncthreads();
    for (int b = t; b < NB; b += 256)
        if (hist[b]) base_l[b] = atomicAdd(&bucket_tail[b], hist[b]);
    __syncthreads();
    for (int e = c0 + t; e < c1; e += 256) {
        int d = dst[e];
        int bkt = d >> 8;
        int idx = atomicAdd(&cursor[bkt], 1);
        binned[base_l[bkt] + idx] =
            make_int4(src[e], __float_as_int(ea[2 * e]), __float_as_int(ea[2 * e + 1]), d);
    }
}

// B: workgroup per bucket -> per-node counts, rowptr, final dst-sorted CSR
__global__ void __launch_bounds__(256) k_binB(const int* __restrict__ bucket_base,
                                              const int4* __restrict__ binned,
                                              int* __restrict__ rowptr,
                                              int4* __restrict__ edges) {
    __shared__ int hist[NPB], pre[NPB], cursor[NPB];
    int b = blockIdx.x, t = threadIdx.x;
    int bb = bucket_base[b], be = bucket_base[b + 1];
    int nb0 = b << 8;
    hist[t] = 0;
    __syncthreads();
    for (int e = bb + t; e < be; e += 256) atomicAdd(&hist[binned[e].w & 255], 1);
    __syncthreads();
    int v = hist[t];
    pre[t] = v;
    __syncthreads();
    for (int off = 1; off < 256; off <<= 1) {
        int x = (t >= off) ? pre[t - off] : 0;
        __syncthreads();
        if (t >= off) pre[t] += x;
        __syncthreads();
    }
    int ex = pre[t] - v;  // exclusive prefix
    if (nb0 + t <= NN) rowptr[nb0 + t] = bb + ex;
    cursor[t] = bb + ex;
    __syncthreads();
    for (int e = bb + t; e < be; e += 256) {
        int4 rec = binned[e];
        int pos = atomicAdd(&cursor[rec.w & 255], 1);
        edges[pos] = rec;
    }
}

// self-loop mean edge_attr per node
__global__ void k_la(const int* __restrict__ rowptr, const int4* __restrict__ edges,
                     float* __restrict__ la) {
    int n = (blockIdx.x * blockDim.x + threadIdx.x) >> 6;
    if (n >= NN) return;
    int lane = threadIdx.x & 63;
    int s0 = rowptr[n], e0 = rowptr[n + 1];
    float a0 = 0.f, a1 = 0.f;
    for (int e = s0 + lane; e < e0; e += 64) {
        int4 ep = edges[e];
        a0 += __int_as_float(ep.y);
        a1 += __int_as_float(ep.z);
    }
#pragma unroll
    for (int off = 32; off > 0; off >>= 1) {
        a0 += __shfl_xor(a0, off);
        a1 += __shfl_xor(a1, off);
    }
    if (lane == 0) {
        float d = fmaxf((float)(e0 - s0), 1.0f);
        la[2 * n] = a0 / d;
        la[2 * n + 1] = a1 / d;
    }
}

// ---------- Me[d,h] scaled by LOG2E ----------
template <int H, int C>
__global__ void k_me(const float* __restrict__ We, const float* __restrict__ aE,
                     float* __restrict__ me) {
    int t = threadIdx.x;
    if (t >= 2 * H) return;
    int d = t / H, hd = t % H;
    float s = 0.f;
    for (int c = 0; c < C; c++) s += We[d * H * C + hd * C + c] * aE[hd * C + c];
    me[t] = s * LOG2E;
}

// layer-1 prep: vS/vD (scaled by LOG2E)
__global__ void k_vsd(const float* __restrict__ W1, const float* __restrict__ aS1,
                      const float* __restrict__ aD1, float* __restrict__ vsd) {
    int t = threadIdx.x;
    if (t >= 40) return;
    const float* a = (t < 20) ? aS1 : aD1;
    int r = t % 20, hd = r / 5, i = r % 5;
    float s = 0.f;
    for (int c = 0; c < 32; c++) s += W1[i * 128 + hd * 32 + c] * a[hd * 32 + c];
    vsd[t] = s * LOG2E;
}

// layer-1 per-node: padded x + logits als1/ald1 (scaled)
__global__ void k_prep1(const float* __restrict__ x, const float* __restrict__ vsd,
                        float4* __restrict__ xp, float4* __restrict__ als1,
                        float4* __restrict__ ald1) {
    int n = blockIdx.x * blockDim.x + threadIdx.x;
    if (n >= NN) return;
    float x0 = x[5 * n], x1 = x[5 * n + 1], x2 = x[5 * n + 2], x3 = x[5 * n + 3],
          x4 = x[5 * n + 4];
    xp[2 * n] = make_float4(x0, x1, x2, x3);
    xp[2 * n + 1] = make_float4(x4, 0.f, 0.f, 0.f);
    float sv[4], dv[4];
#pragma unroll
    for (int hd = 0; hd < 4; hd++) {
        const float* vS = vsd + hd * 5;
        const float* vD = vsd + 20 + hd * 5;
        sv[hd] = x0 * vS[0] + x1 * vS[1] + x2 * vS[2] + x3 * vS[3] + x4 * vS[4];
        dv[hd] = x0 * vD[0] + x1 * vD[1] + x2 * vD[2] + x3 * vD[3] + x4 * vD[4];
    }
    als1[n] = make_float4(sv[0], sv[1], sv[2], sv[3]);
    ald1[n] = make_float4(dv[0], dv[1], dv[2], dv[3]);
}

// ---------- layer 1 agg: thread per (node, head); two-pass softmax; 5-dim x accum ----------
__global__ void k_agg1(const int* __restrict__ rowptr, const int4* __restrict__ edges,
                       const float4* __restrict__ xp, const float* __restrict__ als1,
                       const float* __restrict__ ald1, const float* __restrict__ la,
                       const float* __restrict__ me, float* __restrict__ xw) {
    int t = blockIdx.x * blockDim.x + threadIdx.x;
    if (t >= NN * 4) return;
    int n = t >> 2, hd = t & 3;
    float me0 = me[hd], me1 = me[4 + hd];
    float aldn = ald1[t];
    float aself = lrelu(als1[t] + aldn + la[2 * n] * me0 + la[2 * n + 1] * me1);
    int start = rowptr[n], end = rowptr[n + 1];
    float m = aself;
    for (int e = start; e < end; ++e) {
        int4 ep = edges[e];
        float a = lrelu(als1[ep.x * 4 + hd] + aldn + __int_as_float(ep.y) * me0 +
                        __int_as_float(ep.z) * me1);
        m = fmaxf(m, a);
    }
    float p0 = fexp2(aself - m);
    float den = p0;
    float4 xa = xp[2 * n];
    float xb = xp[2 * n + 1].x;
    float a0 = p0 * xa.x, a1 = p0 * xa.y, a2 = p0 * xa.z, a3 = p0 * xa.w, a4 = p0 * xb;
    for (int e = start; e < end; ++e) {
        int4 ep = edges[e];
        int s = ep.x;
        float a = lrelu(als1[s * 4 + hd] + aldn + __int_as_float(ep.y) * me0 +
                        __int_as_float(ep.z) * me1);
        float p = fexp2(a - m);
        den += p;
        float4 sa = xp[2 * s];
        float sb = xp[2 * s + 1].x;
        a0 += p * sa.x;
        a1 += p * sa.y;
        a2 += p * sa.z;
        a3 += p * sa.w;
        a4 += p * sb;
    }
    float r = 1.f / den;
    float* w = xw + (size_t)n * 20 + hd * 5;
    w[0] = a0 * r;
    w[1] = a1 * r;
    w[2] = a2 * r;
    w[3] = a3 * r;
    w[4] = a4 * r;
}

// ---------- layer 2 transform: register-blocked tile GEMM ----------
__global__ void __launch_bounds__(256) k_l2trans(
        const float* __restrict__ xw, const float* __restrict__ W1,
        const float* __restrict__ b1, const float* __restrict__ W2,
        const float* __restrict__ aS2, const float* __restrict__ aD2,
        float* __restrict__ h2, float* __restrict__ als2, float* __restrict__ ald2) {
    __shared__ float sx[64 * 132];
    int nb = blockIdx.x * 64, t = threadIdx.x;
    {
        int nl = t >> 2, q = t & 3;
        int node = nb + nl;
        float w[20];
        if (node < NN) {
#pragma unroll
            for (int i = 0; i < 20; i++) w[i] = xw[(size_t)node * 20 + i];
        } else {
#pragma unroll
            for (int i = 0; i < 20; i++) w[i] = 0.f;
        }
#pragma unroll
        for (int k = 0; k < 32; k++) {
            int ch = q + 4 * k;
            int hd = ch >> 5;
            float v = w[hd * 5] * W1[ch] + w[hd * 5 + 1] * W1[128 + ch] +
                      w[hd * 5 + 2] * W1[256 + ch] + w[hd * 5 + 3] * W1[384 + ch] +
                      w[hd * 5 + 4] * W1[512 + ch] + b1[ch];
            sx[nl * 132 + ch] = (node < NN) ? elu1(v) : 0.f;
        }
    }
    __syncthreads();
    int jq = t & 15, ng = t >> 4;
    int j4 = jq * 4;
    float4 acc[4];
#pragma unroll
    for (int p = 0; p < 4; p++) acc[p] = make_float4(0.f, 0.f, 0.f, 0.f);
    for (int ic = 0; ic < 128; ic += 4) {
        float4 s[4];
#pragma unroll
        for (int p = 0; p < 4; p++)
            s[p] = *(const float4*)(sx + (ng * 4 + p) * 132 + ic);
#pragma unroll
        for (int r = 0; r < 4; r++) {
            float4 wv = *(const float4*)(W2 + (ic + r) * 64 + j4);
#pragma unroll
            for (int p = 0; p < 4; p++) {
                float sv = (r == 0) ? s[p].x : (r == 1) ? s[p].y : (r == 2) ? s[p].z : s[p].w;
                acc[p].x += sv * wv.x;
                acc[p].y += sv * wv.y;
                acc[p].z += sv * wv.z;
                acc[p].w += sv * wv.w;
            }
        }
    }
    int hd = jq >> 3;
    float4 a_s = *(const float4*)(aS2 + j4);
    float4 a_d = *(const float4*)(aD2 + j4);
    float pS[4], pD[4];
#pragma unroll
    for (int p = 0; p < 4; p++) {
        pS[p] = acc[p].x * a_s.x + acc[p].y * a_s.y + acc[p].z * a_s.z + acc[p].w * a_s.w;
        pD[p] = acc[p].x * a_d.x + acc[p].y * a_d.y + acc[p].z * a_d.z + acc[p].w * a_d.w;
    }
#pragma unroll
    for (int off = 1; off < 8; off <<= 1) {
#pragma unroll
        for (int p = 0; p < 4; p++) {
            pS[p] += __shfl_xor(pS[p], off);
            pD[p] += __shfl_xor(pD[p], off);
        }
    }
#pragma unroll
    for (int p = 0; p < 4; p++) {
        int node = nb + ng * 4 + p;
        if (node < NN) {
            *(float4*)(h2 + (size_t)node * 64 + j4) = acc[p];
            if ((jq & 7) == 0) {
                als2[node * 2 + hd] = pS[p] * LOG2E;
                ald2[node * 2 + hd] = pD[p] * LOG2E;
            }
        }
    }
}

// ---------- layer 2 agg: thread per (node, head-half); two-pass; fused ELU + W3 proj ----------
__global__ void k_agg2(const int* __restrict__ rowptr, const int4* __restrict__ edges,
                       const float* __restrict__ h2, const float* __restrict__ als2,
                       const float* __restrict__ ald2, const float* __restrict__ la,
                       const float* __restrict__ me, const float* __restrict__ b2,
                       const float* __restrict__ W3, float* __restrict__ h3) {
    int t = blockIdx.x * blockDim.x + threadIdx.x;
    if (t >= NN * 4) return;
    int n = t >> 2, sub = t & 3, hd = sub >> 1, qh = sub & 1;
    int cbase = hd * 32 + qh * 16;
    float me0 = me[hd], me1 = me[2 + hd];
    float aldn = ald2[n * 2 + hd];
    float aself = lrelu(als2[n * 2 + hd] + aldn + la[2 * n] * me0 + la[2 * n + 1] * me1);
    int start = rowptr[n], end = rowptr[n + 1];
    float m = aself;
    for (int e = start; e < end; ++e) {
        int4 ep = edges[e];
        float a = lrelu(als2[ep.x * 2 + hd] + aldn + __int_as_float(ep.y) * me0 +
                        __int_as_float(ep.z) * me1);
        m = fmaxf(m, a);
    }
    float p0 = fexp2(aself - m);
    float den = p0;
    float acc[16];
    const float4* hn = (const float4*)(h2 + (size_t)n * 64 + cbase);
#pragma unroll
    for (int q = 0; q < 4; q++) {
        float4 v = hn[q];
        acc[4 * q] = p0 * v.x;
        acc[4 * q + 1] = p0 * v.y;
        acc[4 * q + 2] = p0 * v.z;
        acc[4 * q + 3] = p0 * v.w;
    }
    for (int e = start; e < end; ++e) {
        int4 ep = edges[e];
        int s = ep.x;
        float a = lrelu(als2[s * 2 + hd] + aldn + __int_as_float(ep.y) * me0 +
                        __int_as_float(ep.z) * me1);
        float p = fexp2(a - m);
        den += p;
        const float4* hs = (const float4*)(h2 + (size_t)s * 64 + cbase);
#pragma unroll
        for (int q = 0; q < 4; q++) {
            float4 v = hs[q];
            acc[4 * q] += p * v.x;
            acc[4 * q + 1] += p * v.y;
            acc[4 * q + 2] += p * v.z;
            acc[4 * q + 3] += p * v.w;
        }
    }
    float r = 1.f / den;
    float part = 0.f;
#pragma unroll
    for (int c = 0; c < 16; c++) {
        float v = elu1(acc[c] * r + b2[cbase + c]);
        part += v * W3[cbase + c];
    }
    part += __shfl_xor(part, 1);
    part += __shfl_xor(part, 2);
    if (sub == 0) h3[n] = part;
}

// ---------- layer 3 agg: H=1,C=1; wave per node, lanes parallel over edges ----------
__global__ void k_agg3(const int* __restrict__ rowptr, const int4* __restrict__ edges,
                       const float* __restrict__ h, const float* __restrict__ aS3,
                       const float* __restrict__ aD3, const float* __restrict__ la,
                       const float* __restrict__ me, const float* __restrict__ b,
                       float* __restrict__ out) {
    int n = (blockIdx.x * blockDim.x + threadIdx.x) >> 6;
    if (n >= NN) return;
    int lane = threadIdx.x & 63;
    float me0 = me[0], me1 = me[1];
    float aSs = aS3[0] * LOG2E, aDs = aD3[0] * LOG2E;
    float hn = h[n];
    float ald_n = hn * aDs;
    int start = rowptr[n], end = rowptr[n + 1];
    float m = -1e30f, den = 0.f, num = 0.f;
    for (int e = start + lane; e < end; e += 64) {
        int4 ep = edges[e];
        int s = ep.x;
        float hv = h[s];
        float a = lrelu(hv * aSs + ald_n + __int_as_float(ep.y) * me0 +
                        __int_as_float(ep.z) * me1);
        float mn = fmaxf(m, a);
        float ex = fexp2(-fabsf(a - m));
        bool gt = a > m;
        float sc = gt ? ex : 1.f;
        float p = gt ? 1.f : ex;
        den = den * sc + p;
        num = num * sc + p * hv;
        m = mn;
    }
#pragma unroll
    for (int off = 1; off < 64; off <<= 1) {
        float mo = __shfl_xor(m, off);
        float dn = __shfl_xor(den, off);
        float nm = __shfl_xor(num, off);
        float ex = fexp2(-fabsf(m - mo));
        bool gt = mo > m;
        float s1 = gt ? ex : 1.f;
        float s2 = gt ? 1.f : ex;
        den = den * s1 + dn * s2;
        num = num * s1 + nm * s2;
        m = fmaxf(m, mo);
    }
    if (lane == 0) {
        float aself = lrelu(hn * aSs + ald_n + la[2 * n] * me0 + la[2 * n + 1] * me1);
        float ex = fexp2(-fabsf(aself - m));
        bool gt = aself > m;
        float sc = gt ? ex : 1.f;
        float p = gt ? 1.f : ex;
        den = den * sc + p;
        num = num * sc + p * hn;
        float v = num / den + b[0];
        out[n] = 1.f / (1.f + __expf(-v));
    }
}

extern "C" void kernel_launch(void* const* d_in, const int* in_sizes, int n_in,
                              void* d_out, int out_size, void* d_ws, size_t ws_size,
                              hipStream_t stream) {
    const float* x   = (const float*)d_in[0];
    const int*   ei  = (const int*)d_in[1];
    const float* ea  = (const float*)d_in[2];
    const float* W1  = (const float*)d_in[3];
    const float* aS1 = (const float*)d_in[4];
    const float* aD1 = (const float*)d_in[5];
    const float* We1 = (const float*)d_in[6];
    const float* aE1 = (const float*)d_in[7];
    const float* b1  = (const float*)d_in[8];
    const float* W2  = (const float*)d_in[9];
    const float* aS2 = (const float*)d_in[10];
    const float* aD2 = (const float*)d_in[11];
    const float* We2 = (const float*)d_in[12];
    const float* aE2 = (const float*)d_in[13];
    const float* b2  = (const float*)d_in[14];
    const float* W3  = (const float*)d_in[15];
    const float* aS3 = (const float*)d_in[16];
    const float* aD3 = (const float*)d_in[17];
    const float* We3 = (const float*)d_in[18];
    const float* aE3 = (const float*)d_in[19];
    const float* b3  = (const float*)d_in[20];

    const int* srcv = ei;
    const int* dstv = ei + NE;

    char* basep = (char*)d_ws;
    size_t off = 0;
    auto alloc = [&](size_t nbytes) -> void* {
        void* p = basep + off;
        off += (nbytes + 255) & ~(size_t)255;
        return p;
    };
    int*    bucket_cnt  = (int*)alloc((size_t)(NB + 1) * 4);
    int*    bucket_base = (int*)alloc((size_t)(NB + 1) * 4);
    int*    bucket_tail = (int*)alloc((size_t)(NB + 1) * 4);
    int*    rowptr      = (int*)alloc((size_t)(NN + 1) * 4);
    int4*   binned      = (int4*)alloc((size_t)NE * 16);
    int4*   edges       = (int4*)alloc((size_t)NE * 16);
    float*  la          = (float*)alloc((size_t)NN * 8);
    float*  me          = (float*)alloc(256);
    float*  vsd         = (float*)alloc(256);
    float4* xp          = (float4*)alloc((size_t)NN * 32);
    float4* als1        = (float4*)alloc((size_t)NN * 16);
    float4* ald1        = (float4*)alloc((size_t)NN * 16);
    float*  xw          = (float*)alloc((size_t)NN * 80);
    float*  h2          = (float*)alloc((size_t)NN * 256);
    float*  als2        = (float*)alloc((size_t)NN * 8);
    float*  ald2        = (float*)alloc((size_t)NN * 8);
    float*  h3          = (float*)alloc((size_t)NN * 4);
    (void)ws_size; (void)in_sizes; (void)n_in; (void)out_size;

    auto cdiv = [](long long a, long long b) { return (int)((a + b - 1) / b); };
    const int BS = 256;

    // ---- binned CSR build (once per call; reused by all 3 layers) ----
    hipMemsetAsync(bucket_cnt, 0, (size_t)(NB + 1) * 4, stream);
    k_binA0<<<NCHUNK, 256, 0, stream>>>(dstv, bucket_cnt);
    k_bscan<<<1, 512, 0, stream>>>(bucket_cnt, bucket_base, bucket_tail);
    k_binA2<<<NCHUNK, 256, 0, stream>>>(srcv, dstv, ea, bucket_tail, binned);
    k_binB<<<NB, 256, 0, stream>>>(bucket_base, binned, rowptr, edges);
    k_la<<<cdiv(NN, 4), 256, 0, stream>>>(rowptr, edges, la);

    // ================= Layer 1: IN=5, H=4, C=32 (ELU) =================
    k_me<4, 32><<<1, 64, 0, stream>>>(We1, aE1, me);
    k_vsd<<<1, 64, 0, stream>>>(W1, aS1, aD1, vsd);
    k_prep1<<<cdiv(NN, BS), BS, 0, stream>>>(x, vsd, xp, als1, ald1);
    k_agg1<<<cdiv((long long)NN * 4, BS), BS, 0, stream>>>(rowptr, edges, xp,
                                                           (const float*)als1,
                                                           (const float*)ald1, la, me, xw);

    // ================= Layer 2: IN=128, H=2, C=32 (ELU) =================
    k_l2trans<<<cdiv(NN, 64), 256, 0, stream>>>(xw, W1, b1, W2, aS2, aD2, h2, als2, ald2);
    k_me<2, 32><<<1, 64, 0, stream>>>(We2, aE2, me);
    k_agg2<<<cdiv((long long)NN * 4, BS), BS, 0, stream>>>(rowptr, edges, h2, als2, ald2,
                                                           la, me, b2, W3, h3);

    // ================= Layer 3: IN=64, H=1, C=1 (sigmoid) =================
    k_me<1, 1><<<1, 64, 0, stream>>>(We3, aE3, me);
    k_agg3<<<cdiv(NN, 4), 256, 0, stream>>>(rowptr, edges, h3, aS3, aD3, la, me,
                                            b3, (float*)d_out);
}

// Round 8
// 360.627 us; speedup vs baseline: 48.9217x; 1.2059x over previous
//
#include <hip/hip_runtime.h>
#include <math.h>

#define NN 100000
#define NE 1600000
#define NPB 256                     // nodes per bucket (dst >> 8)
#define NB 391                      // ceil(NN / NPB)
#define NCHUNK 256                  // binning chunks
#define CH ((NE + NCHUNK - 1) / NCHUNK)  // 6250 edges per chunk
#define LOG2E 1.44269504088896f

__device__ __forceinline__ float lrelu(float x) { return fmaxf(x, 0.2f * x); }
__device__ __forceinline__ float elu1(float x) { return x > 0.f ? x : (__expf(x) - 1.f); }
__device__ __forceinline__ float fexp2(float x) {
#if __has_builtin(__builtin_amdgcn_exp2f)
    return __builtin_amdgcn_exp2f(x);
#else
    return exp2f(x);
#endif
}
__device__ __forceinline__ unsigned bf16rne(float f) {
    unsigned u = __float_as_uint(f);
    return (u + 0x7FFFu + ((u >> 16) & 1u)) >> 16;
}
__device__ __forceinline__ float bf16lo(unsigned u) { return __uint_as_float(u << 16); }
__device__ __forceinline__ float bf16hi(unsigned u) {
    return __uint_as_float(u & 0xFFFF0000u);
}

// ================= binned CSR build =================
__global__ void __launch_bounds__(256) k_binA0(const int* __restrict__ dst,
                                               int* __restrict__ bucket_cnt) {
    __shared__ int hist[NB];
    int t = threadIdx.x;
    for (int b = t; b < NB; b += 256) hist[b] = 0;
    __syncthreads();
    int c0 = blockIdx.x * CH, c1 = min(NE, c0 + CH);
    for (int e = c0 + t; e < c1; e += 256) atomicAdd(&hist[dst[e] >> 8], 1);
    __syncthreads();
    for (int b = t; b < NB; b += 256)
        if (hist[b]) atomicAdd(&bucket_cnt[b], hist[b]);
}

__global__ void k_bscan(const int* __restrict__ bucket_cnt, int* __restrict__ bucket_base,
                        int* __restrict__ bucket_tail) {
    __shared__ int s[512];
    int t = threadIdx.x;
    int v = (t < NB) ? bucket_cnt[t] : 0;
    s[t] = v;
    __syncthreads();
    for (int off = 1; off < 512; off <<= 1) {
        int x = (t >= off) ? s[t - off] : 0;
        __syncthreads();
        if (t >= off) s[t] += x;
        __syncthreads();
    }
    if (t < NB) {
        int ex = s[t] - v;
        bucket_base[t] = ex;
        bucket_tail[t] = ex;
        if (t == NB - 1) bucket_base[NB] = s[t];
    }
}

// A2: re-read chunk, reserve per-bucket space, write bucket-grouped 8B records
// rec = {src, bf16(ea0) | bf16(ea1)<<16}; dstb = dst & 255 (1 B)
__global__ void __launch_bounds__(256) k_binA2(const int* __restrict__ src,
                                               const int* __restrict__ dst,
                                               const float* __restrict__ ea,
                                               int* __restrict__ bucket_tail,
                                               uint2* __restrict__ binned,
                                               unsigned char* __restrict__ dstb) {
    __shared__ int hist[NB], base_l[NB], cursor[NB];
    int t = threadIdx.x;
    for (int b = t; b < NB; b += 256) {
        hist[b] = 0;
        cursor[b] = 0;
    }
    __syncthreads();
    int c0 = blockIdx.x * CH, c1 = min(NE, c0 + CH);
    for (int e = c0 + t; e < c1; e += 256) atomicAdd(&hist[dst[e] >> 8], 1);
    __syncthreads();
    for (int b = t; b < NB; b += 256)
        if (hist[b]) base_l[b] = atomicAdd(&bucket_tail[b], hist[b]);
    __syncthreads();
    for (int e = c0 + t; e < c1; e += 256) {
        int d = dst[e];
        int bkt = d >> 8;
        int idx = atomicAdd(&cursor[bkt], 1);
        int pos = base_l[bkt] + idx;
        unsigned pk = bf16rne(ea[2 * e]) | (bf16rne(ea[2 * e + 1]) << 16);
        binned[pos] = make_uint2((unsigned)src[e], pk);
        dstb[pos] = (unsigned char)(d & 255);
    }
}

// B: workgroup per bucket -> rowptr + final dst-sorted CSR (8B records)
__global__ void __launch_bounds__(256) k_binB(const int* __restrict__ bucket_base,
                                              const uint2* __restrict__ binned,
                                              const unsigned char* __restrict__ dstb,
                                              int* __restrict__ rowptr,
                                              uint2* __restrict__ edges) {
    __shared__ int hist[NPB], pre[NPB], cursor[NPB];
    int b = blockIdx.x, t = threadIdx.x;
    int bb = bucket_base[b], be = bucket_base[b + 1];
    int nb0 = b << 8;
    hist[t] = 0;
    __syncthreads();
    for (int e = bb + t; e < be; e += 256) atomicAdd(&hist[dstb[e]], 1);
    __syncthreads();
    int v = hist[t];
    pre[t] = v;
    __syncthreads();
    for (int off = 1; off < 256; off <<= 1) {
        int x = (t >= off) ? pre[t - off] : 0;
        __syncthreads();
        if (t >= off) pre[t] += x;
        __syncthreads();
    }
    int ex = pre[t] - v;
    if (nb0 + t <= NN) rowptr[nb0 + t] = bb + ex;
    cursor[t] = bb + ex;
    __syncthreads();
    for (int e = bb + t; e < be; e += 256) {
        uint2 rec = binned[e];
        int pos = atomicAdd(&cursor[dstb[e]], 1);
        edges[pos] = rec;
    }
}

// self-loop mean edge_attr per node
__global__ void k_la(const int* __restrict__ rowptr, const uint2* __restrict__ edges,
                     float* __restrict__ la) {
    int n = (blockIdx.x * blockDim.x + threadIdx.x) >> 6;
    if (n >= NN) return;
    int lane = threadIdx.x & 63;
    int s0 = rowptr[n], e0 = rowptr[n + 1];
    float a0 = 0.f, a1 = 0.f;
    for (int e = s0 + lane; e < e0; e += 64) {
        unsigned pk = edges[e].y;
        a0 += bf16lo(pk);
        a1 += bf16hi(pk);
    }
#pragma unroll
    for (int off = 32; off > 0; off >>= 1) {
        a0 += __shfl_xor(a0, off);
        a1 += __shfl_xor(a1, off);
    }
    if (lane == 0) {
        float d = fmaxf((float)(e0 - s0), 1.0f);
        la[2 * n] = a0 / d;
        la[2 * n + 1] = a1 / d;
    }
}

// ---------- Me[d,h] scaled by LOG2E ----------
template <int H, int C>
__global__ void k_me(const float* __restrict__ We, const float* __restrict__ aE,
                     float* __restrict__ me) {
    int t = threadIdx.x;
    if (t >= 2 * H) return;
    int d = t / H, hd = t % H;
    float s = 0.f;
    for (int c = 0; c < C; c++) s += We[d * H * C + hd * C + c] * aE[hd * C + c];
    me[t] = s * LOG2E;
}

// layer-1 prep: vS/vD (scaled by LOG2E)
__global__ void k_vsd(const float* __restrict__ W1, const float* __restrict__ aS1,
                      const float* __restrict__ aD1, float* __restrict__ vsd) {
    int t = threadIdx.x;
    if (t >= 40) return;
    const float* a = (t < 20) ? aS1 : aD1;
    int r = t % 20, hd = r / 5, i = r % 5;
    float s = 0.f;
    for (int c = 0; c < 32; c++) s += W1[i * 128 + hd * 32 + c] * a[hd * 32 + c];
    vsd[t] = s * LOG2E;
}

// layer-1 per-node: padded x + logits als1/ald1 (scaled)
__global__ void k_prep1(const float* __restrict__ x, const float* __restrict__ vsd,
                        float4* __restrict__ xp, float4* __restrict__ als1,
                        float4* __restrict__ ald1) {
    int n = blockIdx.x * blockDim.x + threadIdx.x;
    if (n >= NN) return;
    float x0 = x[5 * n], x1 = x[5 * n + 1], x2 = x[5 * n + 2], x3 = x[5 * n + 3],
          x4 = x[5 * n + 4];
    xp[2 * n] = make_float4(x0, x1, x2, x3);
    xp[2 * n + 1] = make_float4(x4, 0.f, 0.f, 0.f);
    float sv[4], dv[4];
#pragma unroll
    for (int hd = 0; hd < 4; hd++) {
        const float* vS = vsd + hd * 5;
        const float* vD = vsd + 20 + hd * 5;
        sv[hd] = x0 * vS[0] + x1 * vS[1] + x2 * vS[2] + x3 * vS[3] + x4 * vS[4];
        dv[hd] = x0 * vD[0] + x1 * vD[1] + x2 * vD[2] + x3 * vD[3] + x4 * vD[4];
    }
    als1[n] = make_float4(sv[0], sv[1], sv[2], sv[3]);
    ald1[n] = make_float4(dv[0], dv[1], dv[2], dv[3]);
}

// ---------- layer 1 agg: thread per (node, head); single pass, m = aself ----------
__global__ void k_agg1(const int* __restrict__ rowptr, const uint2* __restrict__ edges,
                       const float4* __restrict__ xp, const float* __restrict__ als1,
                       const float* __restrict__ ald1, const float* __restrict__ la,
                       const float* __restrict__ me, float* __restrict__ xw) {
    int t = blockIdx.x * blockDim.x + threadIdx.x;
    if (t >= NN * 4) return;
    int n = t >> 2, hd = t & 3;
    float me0 = me[hd], me1 = me[4 + hd];
    float aldn = ald1[t];
    float aself = lrelu(als1[t] + aldn + la[2 * n] * me0 + la[2 * n + 1] * me1);
    int start = rowptr[n], end = rowptr[n + 1];
    float den = 1.f;
    float4 xa = xp[2 * n];
    float xb = xp[2 * n + 1].x;
    float a0 = xa.x, a1 = xa.y, a2 = xa.z, a3 = xa.w, a4 = xb;
    for (int e = start; e < end; ++e) {
        uint2 ep = edges[e];
        int s = (int)ep.x;
        float a = lrelu(als1[s * 4 + hd] + aldn + bf16lo(ep.y) * me0 + bf16hi(ep.y) * me1);
        float p = fexp2(a - aself);
        den += p;
        float4 sa = xp[2 * s];
        float sb = xp[2 * s + 1].x;
        a0 += p * sa.x;
        a1 += p * sa.y;
        a2 += p * sa.z;
        a3 += p * sa.w;
        a4 += p * sb;
    }
    float r = 1.f / den;
    float* w = xw + (size_t)n * 20 + hd * 5;
    w[0] = a0 * r;
    w[1] = a1 * r;
    w[2] = a2 * r;
    w[3] = a3 * r;
    w[4] = a4 * r;
}

// ---------- layer 2 transform: register-blocked tile GEMM; h2 stored bf16 ----------
__global__ void __launch_bounds__(256) k_l2trans(
        const float* __restrict__ xw, const float* __restrict__ W1,
        const float* __restrict__ b1, const float* __restrict__ W2,
        const float* __restrict__ aS2, const float* __restrict__ aD2,
        unsigned short* __restrict__ h2q, float* __restrict__ als2,
        float* __restrict__ ald2) {
    __shared__ float sx[64 * 132];
    int nb = blockIdx.x * 64, t = threadIdx.x;
    {
        int nl = t >> 2, q = t & 3;
        int node = nb + nl;
        float w[20];
        if (node < NN) {
#pragma unroll
            for (int i = 0; i < 20; i++) w[i] = xw[(size_t)node * 20 + i];
        } else {
#pragma unroll
            for (int i = 0; i < 20; i++) w[i] = 0.f;
        }
#pragma unroll
        for (int k = 0; k < 32; k++) {
            int ch = q + 4 * k;
            int hd = ch >> 5;
            float v = w[hd * 5] * W1[ch] + w[hd * 5 + 1] * W1[128 + ch] +
                      w[hd * 5 + 2] * W1[256 + ch] + w[hd * 5 + 3] * W1[384 + ch] +
                      w[hd * 5 + 4] * W1[512 + ch] + b1[ch];
            sx[nl * 132 + ch] = (node < NN) ? elu1(v) : 0.f;
        }
    }
    __syncthreads();
    int jq = t & 15, ng = t >> 4;
    int j4 = jq * 4;
    float4 acc[4];
#pragma unroll
    for (int p = 0; p < 4; p++) acc[p] = make_float4(0.f, 0.f, 0.f, 0.f);
    for (int ic = 0; ic < 128; ic += 4) {
        float4 s[4];
#pragma unroll
        for (int p = 0; p < 4; p++)
            s[p] = *(const float4*)(sx + (ng * 4 + p) * 132 + ic);
#pragma unroll
        for (int r = 0; r < 4; r++) {
            float4 wv = *(const float4*)(W2 + (ic + r) * 64 + j4);
#pragma unroll
            for (int p = 0; p < 4; p++) {
                float sv = (r == 0) ? s[p].x : (r == 1) ? s[p].y : (r == 2) ? s[p].z : s[p].w;
                acc[p].x += sv * wv.x;
                acc[p].y += sv * wv.y;
                acc[p].z += sv * wv.z;
                acc[p].w += sv * wv.w;
            }
        }
    }
    int hd = jq >> 3;
    float4 a_s = *(const float4*)(aS2 + j4);
    float4 a_d = *(const float4*)(aD2 + j4);
    float pS[4], pD[4];
#pragma unroll
    for (int p = 0; p < 4; p++) {
        pS[p] = acc[p].x * a_s.x + acc[p].y * a_s.y + acc[p].z * a_s.z + acc[p].w * a_s.w;
        pD[p] = acc[p].x * a_d.x + acc[p].y * a_d.y + acc[p].z * a_d.z + acc[p].w * a_d.w;
    }
#pragma unroll
    for (int off = 1; off < 8; off <<= 1) {
#pragma unroll
        for (int p = 0; p < 4; p++) {
            pS[p] += __shfl_xor(pS[p], off);
            pD[p] += __shfl_xor(pD[p], off);
        }
    }
#pragma unroll
    for (int p = 0; p < 4; p++) {
        int node = nb + ng * 4 + p;
        if (node < NN) {
            ushort4 q;
            q.x = (unsigned short)bf16rne(acc[p].x);
            q.y = (unsigned short)bf16rne(acc[p].y);
            q.z = (unsigned short)bf16rne(acc[p].z);
            q.w = (unsigned short)bf16rne(acc[p].w);
            *(ushort4*)(h2q + (size_t)node * 64 + j4) = q;
            if ((jq & 7) == 0) {
                als2[node * 2 + hd] = pS[p] * LOG2E;
                ald2[node * 2 + hd] = pD[p] * LOG2E;
            }
        }
    }
}

// ---------- layer 2 agg: thread per (node, head-half); single pass, m = aself ----------
__global__ void k_agg2(const int* __restrict__ rowptr, const uint2* __restrict__ edges,
                       const unsigned short* __restrict__ h2q,
                       const float* __restrict__ als2, const float* __restrict__ ald2,
                       const float* __restrict__ la, const float* __restrict__ me,
                       const float* __restrict__ b2, const float* __restrict__ W3,
                       float* __restrict__ h3) {
    int t = blockIdx.x * blockDim.x + threadIdx.x;
    if (t >= NN * 4) return;
    int n = t >> 2, sub = t & 3, hd = sub >> 1, qh = sub & 1;
    int cbase = hd * 32 + qh * 16;
    float me0 = me[hd], me1 = me[2 + hd];
    float aldn = ald2[n * 2 + hd];
    float aself = lrelu(als2[n * 2 + hd] + aldn + la[2 * n] * me0 + la[2 * n + 1] * me1);
    int start = rowptr[n], end = rowptr[n + 1];
    float den = 1.f;
    float acc[16];
    {
        const uint4* hp = (const uint4*)(h2q + (size_t)n * 64 + cbase);
        uint4 u0 = hp[0], u1 = hp[1];
        acc[0] = bf16lo(u0.x); acc[1] = bf16hi(u0.x);
        acc[2] = bf16lo(u0.y); acc[3] = bf16hi(u0.y);
        acc[4] = bf16lo(u0.z); acc[5] = bf16hi(u0.z);
        acc[6] = bf16lo(u0.w); acc[7] = bf16hi(u0.w);
        acc[8] = bf16lo(u1.x); acc[9] = bf16hi(u1.x);
        acc[10] = bf16lo(u1.y); acc[11] = bf16hi(u1.y);
        acc[12] = bf16lo(u1.z); acc[13] = bf16hi(u1.z);
        acc[14] = bf16lo(u1.w); acc[15] = bf16hi(u1.w);
    }
    for (int e = start; e < end; ++e) {
        uint2 ep = edges[e];
        int s = (int)ep.x;
        float a = lrelu(als2[s * 2 + hd] + aldn + bf16lo(ep.y) * me0 + bf16hi(ep.y) * me1);
        float p = fexp2(a - aself);
        den += p;
        const uint4* sp = (const uint4*)(h2q + (size_t)s * 64 + cbase);
        uint4 u0 = sp[0], u1 = sp[1];
        acc[0] += p * bf16lo(u0.x); acc[1] += p * bf16hi(u0.x);
        acc[2] += p * bf16lo(u0.y); acc[3] += p * bf16hi(u0.y);
        acc[4] += p * bf16lo(u0.z); acc[5] += p * bf16hi(u0.z);
        acc[6] += p * bf16lo(u0.w); acc[7] += p * bf16hi(u0.w);
        acc[8] += p * bf16lo(u1.x); acc[9] += p * bf16hi(u1.x);
        acc[10] += p * bf16lo(u1.y); acc[11] += p * bf16hi(u1.y);
        acc[12] += p * bf16lo(u1.z); acc[13] += p * bf16hi(u1.z);
        acc[14] += p * bf16lo(u1.w); acc[15] += p * bf16hi(u1.w);
    }
    float r = 1.f / den;
    float part = 0.f;
#pragma unroll
    for (int c = 0; c < 16; c++) {
        float v = elu1(acc[c] * r + b2[cbase + c]);
        part += v * W3[cbase + c];
    }
    part += __shfl_xor(part, 1);
    part += __shfl_xor(part, 2);
    if (sub == 0) h3[n] = part;
}

// ---------- layer 3 agg: wave per node, lanes over edges; m = aself ----------
__global__ void k_agg3(const int* __restrict__ rowptr, const uint2* __restrict__ edges,
                       const float* __restrict__ h, const float* __restrict__ aS3,
                       const float* __restrict__ aD3, const float* __restrict__ la,
                       const float* __restrict__ me, const float* __restrict__ b,
                       float* __restrict__ out) {
    int n = (blockIdx.x * blockDim.x + threadIdx.x) >> 6;
    if (n >= NN) return;
    int lane = threadIdx.x & 63;
    float me0 = me[0], me1 = me[1];
    float aSs = aS3[0] * LOG2E, aDs = aD3[0] * LOG2E;
    float hn = h[n];
    float ald_n = hn * aDs;
    float aself = lrelu(hn * aSs + ald_n + la[2 * n] * me0 + la[2 * n + 1] * me1);
    int start = rowptr[n], end = rowptr[n + 1];
    float den = 0.f, num = 0.f;
    for (int e = start + lane; e < end; e += 64) {
        uint2 ep = edges[e];
        int s = (int)ep.x;
        float hv = h[s];
        float a = lrelu(hv * aSs + ald_n + bf16lo(ep.y) * me0 + bf16hi(ep.y) * me1);
        float p = fexp2(a - aself);
        den += p;
        num += p * hv;
    }
#pragma unroll
    for (int off = 32; off > 0; off >>= 1) {
        den += __shfl_xor(den, off);
        num += __shfl_xor(num, off);
    }
    if (lane == 0) {
        den += 1.f;
        num += hn;
        float v = num / den + b[0];
        out[n] = 1.f / (1.f + __expf(-v));
    }
}

extern "C" void kernel_launch(void* const* d_in, const int* in_sizes, int n_in,
                              void* d_out, int out_size, void* d_ws, size_t ws_size,
                              hipStream_t stream) {
    const float* x   = (const float*)d_in[0];
    const int*   ei  = (const int*)d_in[1];
    const float* ea  = (const float*)d_in[2];
    const float* W1  = (const float*)d_in[3];
    const float* aS1 = (const float*)d_in[4];
    const float* aD1 = (const float*)d_in[5];
    const float* We1 = (const float*)d_in[6];
    const float* aE1 = (const float*)d_in[7];
    const float* b1  = (const float*)d_in[8];
    const float* W2  = (const float*)d_in[9];
    const float* aS2 = (const float*)d_in[10];
    const float* aD2 = (const float*)d_in[11];
    const float* We2 = (const float*)d_in[12];
    const float* aE2 = (const float*)d_in[13];
    const float* b2  = (const float*)d_in[14];
    const float* W3  = (const float*)d_in[15];
    const float* aS3 = (const float*)d_in[16];
    const float* aD3 = (const float*)d_in[17];
    const float* We3 = (const float*)d_in[18];
    const float* aE3 = (const float*)d_in[19];
    const float* b3  = (const float*)d_in[20];

    const int* srcv = ei;
    const int* dstv = ei + NE;

    char* basep = (char*)d_ws;
    size_t off = 0;
    auto alloc = [&](size_t nbytes) -> void* {
        void* p = basep + off;
        off += (nbytes + 255) & ~(size_t)255;
        return p;
    };
    int*    bucket_cnt  = (int*)alloc((size_t)(NB + 1) * 4);
    int*    bucket_base = (int*)alloc((size_t)(NB + 1) * 4);
    int*    bucket_tail = (int*)alloc((size_t)(NB + 1) * 4);
    int*    rowptr      = (int*)alloc((size_t)(NN + 1) * 4);
    uint2*  binned      = (uint2*)alloc((size_t)NE * 8);
    unsigned char* dstb = (unsigned char*)alloc((size_t)NE);
    uint2*  edges       = (uint2*)alloc((size_t)NE * 8);
    float*  la          = (float*)alloc((size_t)NN * 8);
    float*  me          = (float*)alloc(256);
    float*  vsd         = (float*)alloc(256);
    float4* xp          = (float4*)alloc((size_t)NN * 32);
    float4* als1        = (float4*)alloc((size_t)NN * 16);
    float4* ald1        = (float4*)alloc((size_t)NN * 16);
    float*  xw          = (float*)alloc((size_t)NN * 80);
    unsigned short* h2q = (unsigned short*)alloc((size_t)NN * 128);
    float*  als2        = (float*)alloc((size_t)NN * 8);
    float*  ald2        = (float*)alloc((size_t)NN * 8);
    float*  h3          = (float*)alloc((size_t)NN * 4);
    (void)ws_size; (void)in_sizes; (void)n_in; (void)out_size;

    auto cdiv = [](long long a, long long b) { return (int)((a + b - 1) / b); };
    const int BS = 256;

    // ---- binned CSR build (once per call; reused by all 3 layers) ----
    hipMemsetAsync(bucket_cnt, 0, (size_t)(NB + 1) * 4, stream);
    k_binA0<<<NCHUNK, 256, 0, stream>>>(dstv, bucket_cnt);
    k_bscan<<<1, 512, 0, stream>>>(bucket_cnt, bucket_base, bucket_tail);
    k_binA2<<<NCHUNK, 256, 0, stream>>>(srcv, dstv, ea, bucket_tail, binned, dstb);
    k_binB<<<NB, 256, 0, stream>>>(bucket_base, binned, dstb, rowptr, edges);
    k_la<<<cdiv(NN, 4), 256, 0, stream>>>(rowptr, edges, la);

    // ================= Layer 1: IN=5, H=4, C=32 (ELU) =================
    k_me<4, 32><<<1, 64, 0, stream>>>(We1, aE1, me);
    k_vsd<<<1, 64, 0, stream>>>(W1, aS1, aD1, vsd);
    k_prep1<<<cdiv(NN, BS), BS, 0, stream>>>(x, vsd, xp, als1, ald1);
    k_agg1<<<cdiv((long long)NN * 4, BS), BS, 0, stream>>>(rowptr, edges, xp,
                                                           (const float*)als1,
                                                           (const float*)ald1, la, me, xw);

    // ================= Layer 2: IN=128, H=2, C=32 (ELU) =================
    k_l2trans<<<cdiv(NN, 64), 256, 0, stream>>>(xw, W1, b1, W2, aS2, aD2, h2q, als2, ald2);
    k_me<2, 32><<<1, 64, 0, stream>>>(We2, aE2, me);
    k_agg2<<<cdiv((long long)NN * 4, BS), BS, 0, stream>>>(rowptr, edges, h2q, als2, ald2,
                                                           la, me, b2, W3, h3);

    // ================= Layer 3: IN=64, H=1, C=1 (sigmoid) =================
    k_me<1, 1><<<1, 64, 0, stream>>>(We3, aE3, me);
    k_agg3<<<cdiv(NN, 4), 256, 0, stream>>>(rowptr, edges, h3, aS3, aD3, la, me,
                                            b3, (float*)d_out);
}